// Round 8
// baseline (681.998 us; speedup 1.0000x reference)
//
#include <hip/hip_runtime.h>

#define NN 300000
#define FF 64
#define EE 2400000
#define FEA 8
#define RAWCAP 131072   // >= 8*129*97 = 100104 guaranteed by IMG_W/H bounds
#define LCAP 2048       // big-bucket bitonic capacity (block path)

typedef unsigned long long ull;

__device__ __forceinline__ unsigned fenc(float f) {
  unsigned b = __float_as_uint(f);
  return (b & 0x80000000u) ? ~b : (b | 0x80000000u);
}
__device__ __forceinline__ float fdec(unsigned e) {
  unsigned b = (e & 0x80000000u) ? (e ^ 0x80000000u) : ~e;
  return __uint_as_float(b);
}

__global__ void init_hdr_k(unsigned* hdr) {
  if (threadIdx.x == 0) {
    hdr[0] = 0xFFFFFFFFu; hdr[1] = 0xFFFFFFFFu;  // min enc
    hdr[2] = 0u;          hdr[3] = 0u;           // max enc
    hdr[9] = 0u;          hdr[10] = 0u;          // compact-list counters
  }
}

// 128 blocks; LDS block-reduce, 4 atomics per block
__global__ void minmax_k(const float* __restrict__ pos, unsigned* hdr) {
  __shared__ unsigned red[4][4];
  int t = blockIdx.x * blockDim.x + threadIdx.x;
  float mnx = 1e30f, mny = 1e30f, mxx = -1e30f, mxy = -1e30f;
  for (int i = t; i < NN; i += gridDim.x * blockDim.x) {
    float px = pos[i * 3 + 1], py = pos[i * 3 + 2];
    mnx = fminf(mnx, px); mny = fminf(mny, py);
    mxx = fmaxf(mxx, px); mxy = fmaxf(mxy, py);
  }
  for (int o = 1; o < 64; o <<= 1) {
    mnx = fminf(mnx, __shfl_xor(mnx, o));
    mny = fminf(mny, __shfl_xor(mny, o));
    mxx = fmaxf(mxx, __shfl_xor(mxx, o));
    mxy = fmaxf(mxy, __shfl_xor(mxy, o));
  }
  int wid = threadIdx.x >> 6;
  if ((threadIdx.x & 63) == 0) {
    red[wid][0] = fenc(mnx); red[wid][1] = fenc(mny);
    red[wid][2] = fenc(mxx); red[wid][3] = fenc(mxy);
  }
  __syncthreads();
  if (threadIdx.x == 0) {
    unsigned a0 = red[0][0], a1 = red[0][1], a2 = red[0][2], a3 = red[0][3];
    for (int k = 1; k < 4; k++) {
      a0 = min(a0, red[k][0]); a1 = min(a1, red[k][1]);
      a2 = max(a2, red[k][2]); a3 = max(a3, red[k][3]);
    }
    atomicMin(&hdr[0], a0); atomicMin(&hdr[1], a1);
    atomicMax(&hdr[2], a2); atomicMax(&hdr[3], a3);
  }
}

__global__ void dims_k(unsigned* hdr) {
  if (threadIdx.x == 0 && blockIdx.x == 0) {
    float mnx = fdec(hdr[0]), mny = fdec(hdr[1]);
    float mxx = fdec(hdr[2]), mxy = fdec(hdr[3]);
    int d0 = (int)(floorf((mxx - mnx) / 5.0f) + 1.0f);
    int d1 = (int)(floorf((mxy - mny) / 5.0f) + 1.0f);
    hdr[4] = (unsigned)d0;
    hdr[5] = (unsigned)d1;
    ((float*)hdr)[6] = mnx;
    ((float*)hdr)[7] = mny;
  }
}

__global__ void raw_k(const float* __restrict__ pos, const int* __restrict__ batch,
                      const unsigned* __restrict__ hdr, int* __restrict__ cluster,
                      unsigned* __restrict__ flags) {
  int i = blockIdx.x * blockDim.x + threadIdx.x;
  if (i >= NN) return;
  float mnx = ((const float*)hdr)[6], mny = ((const float*)hdr)[7];
  int d0 = (int)hdr[4], d1 = (int)hdr[5];
  int c0 = (int)floorf((pos[i * 3 + 1] - mnx) / 5.0f);
  int c1 = (int)floorf((pos[i * 3 + 2] - mny) / 5.0f);
  int raw = batch[i] * (d0 * d1) + c0 * d1 + c1;
  cluster[i] = raw;
  flags[raw] = 1u;
}

// single-kernel exclusive scan: decoupled lookback. desc[b] = flag<<32 | value,
// flag 0=invalid 1=aggregate 2=inclusive-prefix. Reads via atomicAdd(,0) to
// cross the XCD coherence point; <=294 blocks all co-resident -> no deadlock.
__global__ void __launch_bounds__(256)
scan_lb_k(const unsigned* __restrict__ in, unsigned* __restrict__ out, int ntot,
          unsigned* __restrict__ total_out, ull* __restrict__ desc, int nb) {
  __shared__ unsigned sc[256];
  __shared__ unsigned s_pref;
  int bid = blockIdx.x;
  int base = bid * 1024 + threadIdx.x * 4;
  unsigned v[4]; unsigned s = 0;
#pragma unroll
  for (int k = 0; k < 4; k++) {
    int i = base + k;
    v[k] = (i < ntot) ? in[i] : 0u;
    s += v[k];
  }
  sc[threadIdx.x] = s;
  __syncthreads();
  unsigned xv = s;
  for (int o = 1; o < 256; o <<= 1) {
    unsigned y = (threadIdx.x >= o) ? sc[threadIdx.x - o] : 0u;
    __syncthreads();
    xv += y;
    sc[threadIdx.x] = xv;
    __syncthreads();
  }
  unsigned btot = sc[255];
  if (threadIdx.x == 0) {
    unsigned ex = 0;
    if (bid == 0) {
      atomicExch(&desc[0], (2ULL << 32) | (ull)btot);
    } else {
      atomicExch(&desc[bid], (1ULL << 32) | (ull)btot);
      int p = bid - 1;
      while (true) {
        ull d = atomicAdd(&desc[p], 0ULL);
        unsigned fl = (unsigned)(d >> 32);
        if (fl == 2u) { ex += (unsigned)d; break; }
        if (fl == 1u) { ex += (unsigned)d; --p; }
      }
      atomicExch(&desc[bid], (2ULL << 32) | (ull)(ex + btot));
    }
    s_pref = ex;
    if (total_out && bid == nb - 1) *total_out = ex + btot;
  }
  __syncthreads();
  unsigned run = s_pref + xv - s;
#pragma unroll
  for (int k = 0; k < 4; k++) {
    int i = base + k;
    if (i < ntot) out[i] = run;
    run += v[k];
  }
}

// map raw->cluster id and count members per cluster
__global__ void node_cnt_k(const unsigned* __restrict__ rank, int* __restrict__ cluster,
                           unsigned* __restrict__ cnt) {
  int i = blockIdx.x * blockDim.x + threadIdx.x;
  if (i >= NN) return;
  int cl = (int)rank[cluster[i]];
  cluster[i] = cl;
  atomicAdd(&cnt[cl], 1u);
}

__global__ void node_scatter_k(const int* __restrict__ cluster,
                               const unsigned* __restrict__ node_off,
                               unsigned* __restrict__ node_fill,
                               int* __restrict__ nlist) {
  int i = blockIdx.x * blockDim.x + threadIdx.x;
  if (i >= NN) return;
  int cl = cluster[i];
  unsigned p = node_off[cl] + atomicAdd(&node_fill[cl], 1u);
  nlist[p] = i;
}

// one wave per cluster: gather member rows, fmax in registers, write once.
__global__ void __launch_bounds__(256)
cluster_reduce_k(const float* __restrict__ x, const float* __restrict__ pos,
                 const int* __restrict__ batch, const int* __restrict__ nlist,
                 const unsigned* __restrict__ node_off, const unsigned* __restrict__ hdr,
                 float* __restrict__ out_x, float* __restrict__ out_pos,
                 float* __restrict__ out_batch) {
  int w = (blockIdx.x * blockDim.x + threadIdx.x) >> 6;
  int nw = (gridDim.x * blockDim.x) >> 6;
  int f = threadIdx.x & 63;
  int ncl = (int)hdr[8];
  for (int c = w; c < ncl; c += nw) {
    unsigned o0 = node_off[c];
    int len = (int)(node_off[c + 1] - o0);
    float mx = -1e38f;
    long long ps = 0;
    for (int m = 0; m < len; m++) {
      int nd = nlist[o0 + m];
      mx = fmaxf(mx, x[(size_t)nd * FF + f]);
      if (f < 3) ps += (long long)llrintf(pos[nd * 3 + f] * 65536.0f);
    }
    out_x[(size_t)c * FF + f] = mx;
    if (f < 3) {
      float v = (float)((double)ps / 65536.0 / (double)len);
      if (f > 0) v = floorf(v / 4.0f);
      out_pos[c * 3 + f] = v;
    }
    if (f == 63) out_batch[c] = (float)batch[nlist[o0]];
  }
}

// rows >= ncl: zeros for x/pos, -1 for batch (exact-range grid-stride)
__global__ void node_tail_k(const unsigned* __restrict__ hdr,
                            float* __restrict__ out_x, float* __restrict__ out_pos,
                            float* __restrict__ out_batch) {
  int ncl = (int)hdr[8];
  int total = (NN - ncl) * FF;
  for (int i = blockIdx.x * blockDim.x + threadIdx.x; i < total;
       i += gridDim.x * blockDim.x) {
    int r = ncl + (i >> 6), f = i & 63;
    out_x[(size_t)r * FF + f] = 0.0f;
    if (f < 3) out_pos[r * 3 + f] = 0.0f;
    if (f == 0) out_batch[r] = -1.0f;
  }
}

// count + emit packed (b,d) record per edge (sequential, dense write)
__global__ void edge_cnt_pair_k(const int* __restrict__ ei, const int* __restrict__ cluster,
                                unsigned* __restrict__ cs_cnt, ull* __restrict__ erec) {
  int t = blockIdx.x * blockDim.x + threadIdx.x;
  if (t >= EE) return;
  int s = cluster[ei[t]];
  int d = cluster[ei[EE + t]];
  if (s == d) { erec[t] = ~0ULL; return; }   // self-loop: dropped
  atomicAdd(&cs_cnt[s], 1u);
  erec[t] = ((ull)(unsigned)s << 19) | (unsigned)d;
}

// fallback (small ws): count only
__global__ void edge_cnt_k(const int* __restrict__ ei, const int* __restrict__ cluster,
                           unsigned* __restrict__ cs_cnt) {
  int t = blockIdx.x * blockDim.x + threadIdx.x;
  if (t >= EE) return;
  int s = cluster[ei[t]];
  int d = cluster[ei[EE + t]];
  if (s == d) return;
  atomicAdd(&cs_cnt[s], 1u);
}

// pass A: in-place erec (b,d) -> (p,d); sequential r/w, bucket atomics in L2
__global__ void edge_pos_k(ull* __restrict__ erec, const unsigned* __restrict__ cs_off,
                           unsigned* __restrict__ cs_fill) {
  int t = blockIdx.x * blockDim.x + threadIdx.x;
  if (t >= EE) return;
  ull v = erec[t];
  if (v == ~0ULL) return;
  unsigned b = (unsigned)(v >> 19);
  unsigned d = (unsigned)(v & 0x7FFFFULL);
  unsigned p = cs_off[b] + atomicAdd(&cs_fill[b], 1u);
  erec[t] = ((ull)p << 19) | d;
}

// pass B: XCD-sliced placement. 8 block-groups (blockIdx&7 ~ XCD); each streams
// the whole erec (nt loads, L3-resident after first pass) and writes only its
// contiguous 1/8 of keys (~2.4MB, XCD-L2-resident) -> dense 64B write-back.
__global__ void __launch_bounds__(256)
edge_place_k(const ull* __restrict__ erec, const unsigned* __restrict__ cs_off,
             ull* __restrict__ keys) {
  unsigned Etot = cs_off[NN];
  unsigned W = (Etot + 7u) >> 3;
  unsigned g = blockIdx.x & 7;
  unsigned lo = g * W, hi = lo + W;
  int j = blockIdx.x >> 3;
  int stride = (gridDim.x >> 3) * blockDim.x;
  for (int t = j * blockDim.x + threadIdx.x; t < EE; t += stride) {
    ull v = __builtin_nontemporal_load(&erec[t]);
    if (v == ~0ULL) continue;
    unsigned p = (unsigned)(v >> 19);
    if (p < lo || p >= hi) continue;
    unsigned d = (unsigned)(v & 0x7FFFFULL);
    keys[p] = ((ull)d << 22) | (unsigned)t;
  }
}

// fallback: one-pass scatter (round-7 form)
__global__ void edge_scatter_k(const int* __restrict__ ei, const int* __restrict__ cluster,
                               const unsigned* __restrict__ cs_off, unsigned* __restrict__ cs_fill,
                               ull* __restrict__ keys) {
  int t = blockIdx.x * blockDim.x + threadIdx.x;
  if (t >= EE) return;
  int s = cluster[ei[t]];
  int d = cluster[ei[EE + t]];
  if (s == d) return;
  unsigned p = cs_off[s] + atomicAdd(&cs_fill[s], 1u);
  keys[p] = ((ull)(unsigned)d << 22) | (unsigned)t;
}

// split non-empty buckets into small (len<=64) and big; wave-aggregated atomics
__global__ void compact_k(const unsigned* __restrict__ cs_off, unsigned* hdr,
                          int* __restrict__ nb_small, int* __restrict__ nb_big) {
  int b = blockIdx.x * blockDim.x + threadIdx.x;
  int lane = threadIdx.x & 63;
  int len = 0;
  if (b < NN) len = (int)(cs_off[b + 1] - cs_off[b]);
  bool sm = (len > 0) && (len <= 64);
  bool bg = len > 64;
  ull msm = __ballot(sm);
  ull mbg = __ballot(bg);
  unsigned bs = 0, bb = 0;
  if (lane == 0) {
    if (msm) bs = atomicAdd(&hdr[9], (unsigned)__popcll(msm));
    if (mbg) bb = atomicAdd(&hdr[10], (unsigned)__popcll(mbg));
  }
  bs = (unsigned)__shfl((int)bs, 0);
  bb = (unsigned)__shfl((int)bb, 0);
  ull lt = (1ULL << lane) - 1ULL;
  if (sm) nb_small[bs + (unsigned)__popcll(msm & lt)] = b;
  if (bg) nb_big[bb + (unsigned)__popcll(mbg & lt)] = b;
}

// one wave per bucket: head-detect via readlane, store head MASK for emit reuse
__global__ void __launch_bounds__(256)
group_small_k(const ull* __restrict__ keys, const unsigned* __restrict__ cs_off,
              const int* __restrict__ nb_small, const unsigned* __restrict__ hdr,
              unsigned* __restrict__ grp_cnt, ull* __restrict__ headmask) {
  int w = (blockIdx.x * blockDim.x + threadIdx.x) >> 6;
  int nw = (gridDim.x * blockDim.x) >> 6;
  int lane = threadIdx.x & 63;
  int cnt = (int)hdr[9];
  for (int bi = w; bi < cnt; bi += nw) {
    int b = nb_small[bi];
    unsigned o0 = cs_off[b];
    int len = (int)(cs_off[b + 1] - o0);
    unsigned cdv = 0xFFFFFFFFu;
    if (lane < len) cdv = (unsigned)(__builtin_nontemporal_load(&keys[o0 + lane]) >> 22);
    bool head = (lane < len);
    for (int j = 0; j < len; ++j) {
      unsigned cj = (unsigned)__builtin_amdgcn_readlane((int)cdv, j);
      if (cj == cdv && j < lane) head = false;
    }
    ull M = __ballot(head);
    if (lane == 0) {
      grp_cnt[b] = (unsigned)__popcll(M);
      headmask[bi] = M;
    }
  }
}

// one wave per bucket: head mask precomputed; hoisted own-ea load hides gather
// latency under the rank readlane loop; dup-group members merged via reg shfl.
__global__ void __launch_bounds__(256)
emit_small_k(const ull* __restrict__ keys, const unsigned* __restrict__ cs_off,
             const int* __restrict__ nb_small, const unsigned* __restrict__ hdr,
             const unsigned* __restrict__ grp_base, const ull* __restrict__ headmask,
             const float* __restrict__ ea,
             float* __restrict__ out_src, float* __restrict__ out_dst,
             float* __restrict__ out_ea) {
  int w = (blockIdx.x * blockDim.x + threadIdx.x) >> 6;
  int nw = (gridDim.x * blockDim.x) >> 6;
  int lane = threadIdx.x & 63;
  int cnt = (int)hdr[9];
  for (int bi = w; bi < cnt; bi += nw) {
    int b = nb_small[bi];
    unsigned o0 = cs_off[b];
    int len = (int)(cs_off[b + 1] - o0);
    ull M = headmask[bi];
    unsigned cdv = 0xFFFFFFFFu, eidv = 0u;
    if (lane < len) {
      ull key = __builtin_nontemporal_load(&keys[o0 + lane]);
      cdv = (unsigned)(key >> 22);
      eidv = (unsigned)(key & 0x3FFFFFULL);
    }
    float4 v0 = make_float4(0.f, 0.f, 0.f, 0.f), v1 = v0;
    if (lane < len) {
      const float4* p = (const float4*)&ea[(size_t)eidv * FEA];
      v0 = p[0]; v1 = p[1];
    }
    bool head = (M >> lane) & 1ULL;
    bool allsingle = ((int)__popcll(M) == len);
    unsigned r = 0;
    for (int j = 0; j < len; ++j) {
      unsigned cj = (unsigned)__builtin_amdgcn_readlane((int)cdv, j);
      if (((M >> j) & 1ULL) && cj < cdv) r++;
    }
    float4 a0 = v0, a1 = v1;
    if (!allsingle) {
      for (int j = 0; j < len; ++j) {
        unsigned cj = (unsigned)__builtin_amdgcn_readlane((int)cdv, j);
        bool take = (cj == cdv) && (j != lane);
        float t0 = __shfl(v0.x, j), t1 = __shfl(v0.y, j);
        float t2 = __shfl(v0.z, j), t3 = __shfl(v0.w, j);
        float t4 = __shfl(v1.x, j), t5 = __shfl(v1.y, j);
        float t6 = __shfl(v1.z, j), t7 = __shfl(v1.w, j);
        if (take) {
          a0.x += t0; a0.y += t1; a0.z += t2; a0.w += t3;
          a1.x += t4; a1.y += t5; a1.z += t6; a1.w += t7;
        }
      }
    }
    if (head) {
      unsigned row = grp_base[b] + r;
      out_src[row] = (float)b;
      out_dst[row] = (float)cdv;
      float4* o = (float4*)&out_ea[(size_t)row * FEA];
      o[0] = a0; o[1] = a1;
    }
  }
}

__global__ void __launch_bounds__(256)
sort_big_k(ull* __restrict__ keys, const unsigned* __restrict__ cs_off,
           const int* __restrict__ nb_big, const unsigned* __restrict__ hdr,
           unsigned* __restrict__ grp_cnt) {
  __shared__ ull sm[LCAP];
  __shared__ ull rb[256];
  __shared__ int ri[256];
  __shared__ unsigned s4[4];
  int nbig = (int)hdr[10];
  for (int bi = blockIdx.x; bi < nbig; bi += gridDim.x) {
    int b = nb_big[bi];
    unsigned o0 = cs_off[b];
    int len = (int)(cs_off[b + 1] - o0);
    if (len <= LCAP) {
      int np = 1; while (np < len) np <<= 1;
      for (int i = threadIdx.x; i < np; i += 256)
        sm[i] = (i < len) ? keys[o0 + i] : ~0ULL;
      __syncthreads();
      for (int k = 2; k <= np; k <<= 1) {
        for (int j = k >> 1; j > 0; j >>= 1) {
          for (int i = threadIdx.x; i < np; i += 256) {
            int ixj = i ^ j;
            if (ixj > i) {
              ull a = sm[i], c = sm[ixj];
              bool up = ((i & k) == 0);
              if (up ? (a > c) : (a < c)) { sm[i] = c; sm[ixj] = a; }
            }
          }
          __syncthreads();
        }
      }
      unsigned g = 0;
      for (int i = threadIdx.x; i < len; i += 256) {
        ull kk = sm[i];
        keys[o0 + i] = kk;
        unsigned cd = (unsigned)(kk >> 22);
        if (i == 0 || (unsigned)(sm[i - 1] >> 22) != cd) g++;
      }
      for (int o = 32; o > 0; o >>= 1) g += __shfl_down(g, o);
      if ((threadIdx.x & 63) == 0) s4[threadIdx.x >> 6] = g;
      __syncthreads();
      if (threadIdx.x == 0) grp_cnt[b] = s4[0] + s4[1] + s4[2] + s4[3];
      __syncthreads();
    } else {
      for (int p = 0; p < len - 1; p++) {
        ull best = ~0ULL; int bidx = -1;
        for (int i = p + threadIdx.x; i < len; i += 256) {
          ull v = keys[o0 + i];
          if (v < best) { best = v; bidx = i; }
        }
        rb[threadIdx.x] = best; ri[threadIdx.x] = bidx;
        __syncthreads();
        for (int sd = 128; sd > 0; sd >>= 1) {
          if (threadIdx.x < sd && rb[threadIdx.x + sd] < rb[threadIdx.x]) {
            rb[threadIdx.x] = rb[threadIdx.x + sd]; ri[threadIdx.x] = ri[threadIdx.x + sd];
          }
          __syncthreads();
        }
        if (threadIdx.x == 0) {
          int m = ri[0];
          ull tmp = keys[o0 + p];
          keys[o0 + p] = rb[0];
          keys[o0 + m] = tmp;
        }
        __syncthreads();
      }
      unsigned g = 0;
      for (int i = threadIdx.x; i < len; i += 256) {
        unsigned cd = (unsigned)(keys[o0 + i] >> 22);
        if (i == 0 || (unsigned)(keys[o0 + i - 1] >> 22) != cd) g++;
      }
      for (int o = 32; o > 0; o >>= 1) g += __shfl_down(g, o);
      if ((threadIdx.x & 63) == 0) s4[threadIdx.x >> 6] = g;
      __syncthreads();
      if (threadIdx.x == 0) grp_cnt[b] = s4[0] + s4[1] + s4[2] + s4[3];
      __syncthreads();
    }
  }
}

__global__ void __launch_bounds__(256)
emit_big_k(const ull* __restrict__ keys, const unsigned* __restrict__ cs_off,
           const int* __restrict__ nb_big, const unsigned* __restrict__ hdr,
           const unsigned* __restrict__ grp_base, const float* __restrict__ ea,
           float* __restrict__ out_src, float* __restrict__ out_dst,
           float* __restrict__ out_ea) {
  __shared__ unsigned sc[256];
  __shared__ unsigned s_carry;
  int nbig = (int)hdr[10];
  for (int bi = blockIdx.x; bi < nbig; bi += gridDim.x) {
    int b = nb_big[bi];
    unsigned o0 = cs_off[b];
    int len = (int)(cs_off[b + 1] - o0);
    unsigned base = grp_base[b];
    if (threadIdx.x == 0) s_carry = 0;
    __syncthreads();
    for (int c0 = 0; c0 < len; c0 += 256) {
      int i = c0 + threadIdx.x;
      unsigned cd = 0; bool newg = false;
      if (i < len) {
        ull kk = keys[o0 + i];
        cd = (unsigned)(kk >> 22);
        newg = (i == 0) || ((unsigned)(keys[o0 + i - 1] >> 22) != cd);
      }
      unsigned flag = newg ? 1u : 0u;
      sc[threadIdx.x] = flag;
      __syncthreads();
      unsigned xv = flag;
      for (int o = 1; o < 256; o <<= 1) {
        unsigned y = (threadIdx.x >= o) ? sc[threadIdx.x - o] : 0u;
        __syncthreads();
        xv += y;
        sc[threadIdx.x] = xv;
        __syncthreads();
      }
      unsigned carry_old = s_carry;
      if (newg) {
        float a0=0,a1=0,a2=0,a3=0,a4=0,a5=0,a6=0,a7=0;
        int j = i;
        while (j < len) {
          ull k2 = keys[o0 + j];
          if ((unsigned)(k2 >> 22) != cd) break;
          unsigned eid = (unsigned)(k2 & 0x3FFFFFULL);
          const float* p = &ea[(size_t)eid * FEA];
          a0+=p[0];a1+=p[1];a2+=p[2];a3+=p[3];a4+=p[4];a5+=p[5];a6+=p[6];a7+=p[7];
          j++;
        }
        unsigned row = base + carry_old + xv - 1u;
        out_src[row] = (float)b;
        out_dst[row] = (float)cd;
        float* q = &out_ea[(size_t)row * FEA];
        q[0]=a0;q[1]=a1;q[2]=a2;q[3]=a3;q[4]=a4;q[5]=a5;q[6]=a6;q[7]=a7;
      }
      __syncthreads();
      if (threadIdx.x == 255) s_carry = carry_old + xv;
      __syncthreads();
    }
  }
}

// rows >= T (total groups) get -1/-1 and zero ea (exact-range grid-stride)
__global__ void tail_fill_k(const unsigned* __restrict__ grp_base,
                            float* __restrict__ out_src, float* __restrict__ out_dst,
                            float* __restrict__ out_ea) {
  int T = (int)grp_base[NN];
  for (int t = T + blockIdx.x * blockDim.x + threadIdx.x; t < EE;
       t += gridDim.x * blockDim.x) {
    out_src[t] = -1.0f;
    out_dst[t] = -1.0f;
    float4 z = make_float4(0.f, 0.f, 0.f, 0.f);
    float4* o = (float4*)&out_ea[(size_t)t * FEA];
    o[0] = z; o[1] = z;
  }
}

extern "C" void kernel_launch(void* const* d_in, const int* in_sizes, int n_in,
                              void* d_out, int out_size, void* d_ws, size_t ws_size,
                              hipStream_t stream) {
  const float* x   = (const float*)d_in[0];
  const float* pos = (const float*)d_in[1];
  const int* batch = (const int*)d_in[2];
  const int* ei    = (const int*)d_in[3];
  const float* ea  = (const float*)d_in[4];
  float* out = (float*)d_out;

  const size_t OX = 0;
  const size_t OP = (size_t)NN * FF;
  const size_t OB = OP + (size_t)NN * 3;
  const size_t OE = OB + (size_t)NN;
  const size_t OA = OE + (size_t)2 * EE;

  char* w = (char*)d_ws;
  size_t woff = 0;
  auto alloc = [&](size_t bytes) -> void* {
    void* p = w + woff;
    woff += (bytes + 255) & ~(size_t)255;
    return p;
  };
  // zeroed region (one memset)
  unsigned* rank    = (unsigned*)alloc((size_t)RAWCAP * 4);     // reuse: nb_big
  unsigned* cnt     = (unsigned*)alloc((size_t)(NN + 1) * 4);   // reuse: nb_small
  unsigned* node_fill = (unsigned*)alloc((size_t)NN * 4);
  unsigned* cs_cnt  = (unsigned*)alloc((size_t)(NN + 1) * 4);
  unsigned* cs_fill = (unsigned*)alloc((size_t)(NN + 1) * 4);
  unsigned* grp_cnt = (unsigned*)alloc((size_t)(NN + 1) * 4);
  ull* desc0        = (ull*)alloc(512 * 8);
  ull* desc1        = (ull*)alloc(512 * 8);
  ull* desc2        = (ull*)alloc(512 * 8);
  ull* desc3        = (ull*)alloc(512 * 8);
  size_t zero_bytes = woff;
  // written-before-read region
  int* cluster      = (int*)alloc((size_t)NN * 4);
  int* nlist        = (int*)alloc((size_t)NN * 4);
  unsigned* node_off= (unsigned*)alloc((size_t)(NN + 2) * 4);
  unsigned* cs_off  = (unsigned*)alloc((size_t)(NN + 2) * 4);
  unsigned* grp_base= (unsigned*)alloc((size_t)(NN + 2) * 4);
  unsigned* hdr     = (unsigned*)alloc(256);
  ull* headmask     = (ull*)alloc((size_t)NN * 8);
  ull* keys         = (ull*)alloc((size_t)EE * 8);
  ull* erec         = (ull*)alloc((size_t)EE * 8);   // two-pass staging (optional)
  bool twopass = (ws_size >= woff);

  int* nb_small = (int*)cnt;    // dead after node_off scan
  int* nb_big   = (int*)rank;   // dead after node_cnt_k

  hipMemsetAsync(d_ws, 0, zero_bytes, stream);

  init_hdr_k<<<1, 64, 0, stream>>>(hdr);
  minmax_k<<<128, 256, 0, stream>>>(pos, hdr);
  dims_k<<<1, 64, 0, stream>>>(hdr);
  raw_k<<<(NN + 255) / 256, 256, 0, stream>>>(pos, batch, hdr, cluster, rank);

  auto scan1 = [&](const unsigned* in_, unsigned* out_, int ntot,
                   unsigned* total_out, ull* d_) {
    int nb = (ntot + 1023) / 1024;
    scan_lb_k<<<nb, 256, 0, stream>>>(in_, out_, ntot, total_out, d_, nb);
  };
  scan1(rank, rank, RAWCAP, hdr + 8, desc0);   // rank[raw] = cluster id; total -> ncl

  node_cnt_k<<<(NN + 255) / 256, 256, 0, stream>>>(rank, cluster, cnt);
  scan1(cnt, node_off, NN + 1, nullptr, desc1);
  node_scatter_k<<<(NN + 255) / 256, 256, 0, stream>>>(cluster, node_off, node_fill, nlist);
  cluster_reduce_k<<<2048, 256, 0, stream>>>(x, pos, batch, nlist, node_off, hdr,
                                             out + OX, out + OP, out + OB);
  node_tail_k<<<2048, 256, 0, stream>>>(hdr, out + OX, out + OP, out + OB);

  if (twopass) {
    edge_cnt_pair_k<<<(EE + 255) / 256, 256, 0, stream>>>(ei, cluster, cs_cnt, erec);
  } else {
    edge_cnt_k<<<(EE + 255) / 256, 256, 0, stream>>>(ei, cluster, cs_cnt);
  }
  scan1(cs_cnt, cs_off, NN + 1, nullptr, desc2);
  if (twopass) {
    edge_pos_k<<<(EE + 255) / 256, 256, 0, stream>>>(erec, cs_off, cs_fill);
    edge_place_k<<<2048, 256, 0, stream>>>(erec, cs_off, keys);
  } else {
    edge_scatter_k<<<(EE + 255) / 256, 256, 0, stream>>>(ei, cluster, cs_off, cs_fill, keys);
  }

  compact_k<<<(NN + 255) / 256, 256, 0, stream>>>(cs_off, hdr, nb_small, nb_big);
  group_small_k<<<2048, 256, 0, stream>>>(keys, cs_off, nb_small, hdr, grp_cnt, headmask);
  sort_big_k<<<256, 256, 0, stream>>>(keys, cs_off, nb_big, hdr, grp_cnt);
  scan1(grp_cnt, grp_base, NN + 1, nullptr, desc3);
  emit_small_k<<<4096, 256, 0, stream>>>(keys, cs_off, nb_small, hdr, grp_base, headmask, ea,
                                         out + OE, out + OE + EE, out + OA);
  emit_big_k<<<256, 256, 0, stream>>>(keys, cs_off, nb_big, hdr, grp_base, ea,
                                      out + OE, out + OE + EE, out + OA);
  tail_fill_k<<<512, 256, 0, stream>>>(grp_base, out + OE, out + OE + EE, out + OA);
}

// Round 9
// 670.338 us; speedup vs baseline: 1.0174x; 1.0174x over previous
//
#include <hip/hip_runtime.h>

#define NN 300000
#define FF 64
#define EE 2400000
#define FEA 8
#define RAWCAP 131072   // >= 8*129*97 = 100104 guaranteed by IMG_W/H bounds
#define LCAP 2048       // big-bucket bitonic capacity (block path)

typedef unsigned long long ull;

__device__ __forceinline__ unsigned fenc(float f) {
  unsigned b = __float_as_uint(f);
  return (b & 0x80000000u) ? ~b : (b | 0x80000000u);
}
__device__ __forceinline__ float fdec(unsigned e) {
  unsigned b = (e & 0x80000000u) ? (e ^ 0x80000000u) : ~e;
  return __uint_as_float(b);
}

__global__ void init_hdr_k(unsigned* hdr) {
  if (threadIdx.x == 0) {
    hdr[0] = 0xFFFFFFFFu; hdr[1] = 0xFFFFFFFFu;  // min enc
    hdr[2] = 0u;          hdr[3] = 0u;           // max enc
    hdr[9] = 0u;          hdr[10] = 0u;          // compact-list counters
  }
}

// 128 blocks; LDS block-reduce, 4 atomics per block
__global__ void minmax_k(const float* __restrict__ pos, unsigned* hdr) {
  __shared__ unsigned red[4][4];
  int t = blockIdx.x * blockDim.x + threadIdx.x;
  float mnx = 1e30f, mny = 1e30f, mxx = -1e30f, mxy = -1e30f;
  for (int i = t; i < NN; i += gridDim.x * blockDim.x) {
    float px = pos[i * 3 + 1], py = pos[i * 3 + 2];
    mnx = fminf(mnx, px); mny = fminf(mny, py);
    mxx = fmaxf(mxx, px); mxy = fmaxf(mxy, py);
  }
  for (int o = 1; o < 64; o <<= 1) {
    mnx = fminf(mnx, __shfl_xor(mnx, o));
    mny = fminf(mny, __shfl_xor(mny, o));
    mxx = fmaxf(mxx, __shfl_xor(mxx, o));
    mxy = fmaxf(mxy, __shfl_xor(mxy, o));
  }
  int wid = threadIdx.x >> 6;
  if ((threadIdx.x & 63) == 0) {
    red[wid][0] = fenc(mnx); red[wid][1] = fenc(mny);
    red[wid][2] = fenc(mxx); red[wid][3] = fenc(mxy);
  }
  __syncthreads();
  if (threadIdx.x == 0) {
    unsigned a0 = red[0][0], a1 = red[0][1], a2 = red[0][2], a3 = red[0][3];
    for (int k = 1; k < 4; k++) {
      a0 = min(a0, red[k][0]); a1 = min(a1, red[k][1]);
      a2 = max(a2, red[k][2]); a3 = max(a3, red[k][3]);
    }
    atomicMin(&hdr[0], a0); atomicMin(&hdr[1], a1);
    atomicMax(&hdr[2], a2); atomicMax(&hdr[3], a3);
  }
}

__global__ void dims_k(unsigned* hdr) {
  if (threadIdx.x == 0 && blockIdx.x == 0) {
    float mnx = fdec(hdr[0]), mny = fdec(hdr[1]);
    float mxx = fdec(hdr[2]), mxy = fdec(hdr[3]);
    int d0 = (int)(floorf((mxx - mnx) / 5.0f) + 1.0f);
    int d1 = (int)(floorf((mxy - mny) / 5.0f) + 1.0f);
    hdr[4] = (unsigned)d0;
    hdr[5] = (unsigned)d1;
    ((float*)hdr)[6] = mnx;
    ((float*)hdr)[7] = mny;
  }
}

__global__ void raw_k(const float* __restrict__ pos, const int* __restrict__ batch,
                      const unsigned* __restrict__ hdr, int* __restrict__ cluster,
                      unsigned* __restrict__ flags) {
  int i = blockIdx.x * blockDim.x + threadIdx.x;
  if (i >= NN) return;
  float mnx = ((const float*)hdr)[6], mny = ((const float*)hdr)[7];
  int d0 = (int)hdr[4], d1 = (int)hdr[5];
  int c0 = (int)floorf((pos[i * 3 + 1] - mnx) / 5.0f);
  int c1 = (int)floorf((pos[i * 3 + 2] - mny) / 5.0f);
  int raw = batch[i] * (d0 * d1) + c0 * d1 + c1;
  cluster[i] = raw;
  flags[raw] = 1u;
}

// single-kernel exclusive scan: decoupled lookback (validated round 8).
__global__ void __launch_bounds__(256)
scan_lb_k(const unsigned* __restrict__ in, unsigned* __restrict__ out, int ntot,
          unsigned* __restrict__ total_out, ull* __restrict__ desc, int nb) {
  __shared__ unsigned sc[256];
  __shared__ unsigned s_pref;
  int bid = blockIdx.x;
  int base = bid * 1024 + threadIdx.x * 4;
  unsigned v[4]; unsigned s = 0;
#pragma unroll
  for (int k = 0; k < 4; k++) {
    int i = base + k;
    v[k] = (i < ntot) ? in[i] : 0u;
    s += v[k];
  }
  sc[threadIdx.x] = s;
  __syncthreads();
  unsigned xv = s;
  for (int o = 1; o < 256; o <<= 1) {
    unsigned y = (threadIdx.x >= o) ? sc[threadIdx.x - o] : 0u;
    __syncthreads();
    xv += y;
    sc[threadIdx.x] = xv;
    __syncthreads();
  }
  unsigned btot = sc[255];
  if (threadIdx.x == 0) {
    unsigned ex = 0;
    if (bid == 0) {
      atomicExch(&desc[0], (2ULL << 32) | (ull)btot);
    } else {
      atomicExch(&desc[bid], (1ULL << 32) | (ull)btot);
      int p = bid - 1;
      while (true) {
        ull d = atomicAdd(&desc[p], 0ULL);
        unsigned fl = (unsigned)(d >> 32);
        if (fl == 2u) { ex += (unsigned)d; break; }
        if (fl == 1u) { ex += (unsigned)d; --p; }
      }
      atomicExch(&desc[bid], (2ULL << 32) | (ull)(ex + btot));
    }
    s_pref = ex;
    if (total_out && bid == nb - 1) *total_out = ex + btot;
  }
  __syncthreads();
  unsigned run = s_pref + xv - s;
#pragma unroll
  for (int k = 0; k < 4; k++) {
    int i = base + k;
    if (i < ntot) out[i] = run;
    run += v[k];
  }
}

// map raw->cluster id and count members per cluster
__global__ void node_cnt_k(const unsigned* __restrict__ rank, int* __restrict__ cluster,
                           unsigned* __restrict__ cnt) {
  int i = blockIdx.x * blockDim.x + threadIdx.x;
  if (i >= NN) return;
  int cl = (int)rank[cluster[i]];
  cluster[i] = cl;
  atomicAdd(&cnt[cl], 1u);
}

__global__ void node_scatter_k(const int* __restrict__ cluster,
                               const unsigned* __restrict__ node_off,
                               unsigned* __restrict__ node_fill,
                               int* __restrict__ nlist) {
  int i = blockIdx.x * blockDim.x + threadIdx.x;
  if (i >= NN) return;
  int cl = cluster[i];
  unsigned p = node_off[cl] + atomicAdd(&node_fill[cl], 1u);
  nlist[p] = i;
}

// one wave per cluster: gather member rows, fmax in registers, write once.
__global__ void __launch_bounds__(256)
cluster_reduce_k(const float* __restrict__ x, const float* __restrict__ pos,
                 const int* __restrict__ batch, const int* __restrict__ nlist,
                 const unsigned* __restrict__ node_off, const unsigned* __restrict__ hdr,
                 float* __restrict__ out_x, float* __restrict__ out_pos,
                 float* __restrict__ out_batch) {
  int w = (blockIdx.x * blockDim.x + threadIdx.x) >> 6;
  int nw = (gridDim.x * blockDim.x) >> 6;
  int f = threadIdx.x & 63;
  int ncl = (int)hdr[8];
  for (int c = w; c < ncl; c += nw) {
    unsigned o0 = node_off[c];
    int len = (int)(node_off[c + 1] - o0);
    float mx = -1e38f;
    long long ps = 0;
    for (int m = 0; m < len; m++) {
      int nd = nlist[o0 + m];
      mx = fmaxf(mx, x[(size_t)nd * FF + f]);
      if (f < 3) ps += (long long)llrintf(pos[nd * 3 + f] * 65536.0f);
    }
    out_x[(size_t)c * FF + f] = mx;
    if (f < 3) {
      float v = (float)((double)ps / 65536.0 / (double)len);
      if (f > 0) v = floorf(v / 4.0f);
      out_pos[c * 3 + f] = v;
    }
    if (f == 63) out_batch[c] = (float)batch[nlist[o0]];
  }
}

// rows >= ncl: zeros for x/pos, -1 for batch (exact-range grid-stride)
__global__ void node_tail_k(const unsigned* __restrict__ hdr,
                            float* __restrict__ out_x, float* __restrict__ out_pos,
                            float* __restrict__ out_batch) {
  int ncl = (int)hdr[8];
  int total = (NN - ncl) * FF;
  for (int i = blockIdx.x * blockDim.x + threadIdx.x; i < total;
       i += gridDim.x * blockDim.x) {
    int r = ncl + (i >> 6), f = i & 63;
    out_x[(size_t)r * FF + f] = 0.0f;
    if (f < 3) out_pos[r * 3 + f] = 0.0f;
    if (f == 0) out_batch[r] = -1.0f;
  }
}

// ONE atomic pass: count, and keep the returned within-bucket slot r.
// erec[t] = r(22b) << 36 | s(19b) << 17 | d(17b); d < 131072 = 2^17 guaranteed.
__global__ void edge_cnt_pair_k(const int* __restrict__ ei, const int* __restrict__ cluster,
                                unsigned* __restrict__ cs_cnt, ull* __restrict__ erec) {
  int t = blockIdx.x * blockDim.x + threadIdx.x;
  if (t >= EE) return;
  int s = cluster[ei[t]];
  int d = cluster[ei[EE + t]];
  if (s == d) { erec[t] = ~0ULL; return; }   // self-loop: dropped
  unsigned r = atomicAdd(&cs_cnt[s], 1u);
  erec[t] = ((ull)r << 36) | ((ull)(unsigned)s << 17) | (unsigned)d;
}

// fallback (small ws): count only
__global__ void edge_cnt_k(const int* __restrict__ ei, const int* __restrict__ cluster,
                           unsigned* __restrict__ cs_cnt) {
  int t = blockIdx.x * blockDim.x + threadIdx.x;
  if (t >= EE) return;
  int s = cluster[ei[t]];
  int d = cluster[ei[EE + t]];
  if (s == d) return;
  atomicAdd(&cs_cnt[s], 1u);
}

// atomic-free XCD-sliced placement: 8 block-groups; each streams erec (nt
// sequential loads, L3-resident after first touch) and writes only its
// contiguous 1/8 of keys (~2.4MB, XCD-L2-resident) -> dense 64B write-back.
__global__ void __launch_bounds__(256)
edge_place_k(const ull* __restrict__ erec, const unsigned* __restrict__ cs_off,
             ull* __restrict__ keys) {
  unsigned Etot = cs_off[NN];
  unsigned W = (Etot + 7u) >> 3;
  unsigned g = blockIdx.x & 7;
  unsigned lo = g * W, hi = lo + W;
  int j = blockIdx.x >> 3;
  int stride = (gridDim.x >> 3) * blockDim.x;
  for (int t = j * blockDim.x + threadIdx.x; t < EE; t += stride) {
    ull v = __builtin_nontemporal_load(&erec[t]);
    if (v == ~0ULL) continue;
    unsigned s = (unsigned)((v >> 17) & 0x7FFFFULL);
    unsigned p = cs_off[s] + (unsigned)(v >> 36);
    if (p < lo || p >= hi) continue;
    unsigned d = (unsigned)(v & 0x1FFFFULL);
    keys[p] = ((ull)d << 22) | (unsigned)t;
  }
}

// fallback: one-pass scatter (round-7 form)
__global__ void edge_scatter_k(const int* __restrict__ ei, const int* __restrict__ cluster,
                               const unsigned* __restrict__ cs_off, unsigned* __restrict__ cs_fill,
                               ull* __restrict__ keys) {
  int t = blockIdx.x * blockDim.x + threadIdx.x;
  if (t >= EE) return;
  int s = cluster[ei[t]];
  int d = cluster[ei[EE + t]];
  if (s == d) return;
  unsigned p = cs_off[s] + atomicAdd(&cs_fill[s], 1u);
  keys[p] = ((ull)(unsigned)d << 22) | (unsigned)t;
}

// split non-empty buckets into small (len<=64) and big; wave-aggregated atomics
__global__ void compact_k(const unsigned* __restrict__ cs_off, unsigned* hdr,
                          int* __restrict__ nb_small, int* __restrict__ nb_big) {
  int b = blockIdx.x * blockDim.x + threadIdx.x;
  int lane = threadIdx.x & 63;
  int len = 0;
  if (b < NN) len = (int)(cs_off[b + 1] - cs_off[b]);
  bool sm = (len > 0) && (len <= 64);
  bool bg = len > 64;
  ull msm = __ballot(sm);
  ull mbg = __ballot(bg);
  unsigned bs = 0, bb = 0;
  if (lane == 0) {
    if (msm) bs = atomicAdd(&hdr[9], (unsigned)__popcll(msm));
    if (mbg) bb = atomicAdd(&hdr[10], (unsigned)__popcll(mbg));
  }
  bs = (unsigned)__shfl((int)bs, 0);
  bb = (unsigned)__shfl((int)bb, 0);
  ull lt = (1ULL << lane) - 1ULL;
  if (sm) nb_small[bs + (unsigned)__popcll(msm & lt)] = b;
  if (bg) nb_big[bb + (unsigned)__popcll(mbg & lt)] = b;
}

// one wave per bucket: head-detect via readlane, store head MASK for emit reuse
__global__ void __launch_bounds__(256)
group_small_k(const ull* __restrict__ keys, const unsigned* __restrict__ cs_off,
              const int* __restrict__ nb_small, const unsigned* __restrict__ hdr,
              unsigned* __restrict__ grp_cnt, ull* __restrict__ headmask) {
  int w = (blockIdx.x * blockDim.x + threadIdx.x) >> 6;
  int nw = (gridDim.x * blockDim.x) >> 6;
  int lane = threadIdx.x & 63;
  int cnt = (int)hdr[9];
  for (int bi = w; bi < cnt; bi += nw) {
    int b = nb_small[bi];
    unsigned o0 = cs_off[b];
    int len = (int)(cs_off[b + 1] - o0);
    unsigned cdv = 0xFFFFFFFFu;
    if (lane < len) cdv = (unsigned)(__builtin_nontemporal_load(&keys[o0 + lane]) >> 22);
    bool head = (lane < len);
    for (int j = 0; j < len; ++j) {
      unsigned cj = (unsigned)__builtin_amdgcn_readlane((int)cdv, j);
      if (cj == cdv && j < lane) head = false;
    }
    ull M = __ballot(head);
    if (lane == 0) {
      grp_cnt[b] = (unsigned)__popcll(M);
      headmask[bi] = M;
    }
  }
}

// one wave per bucket: head mask precomputed; hoisted own-ea load hides gather
// latency under the rank readlane loop; dup-group members merged via reg shfl.
__global__ void __launch_bounds__(256)
emit_small_k(const ull* __restrict__ keys, const unsigned* __restrict__ cs_off,
             const int* __restrict__ nb_small, const unsigned* __restrict__ hdr,
             const unsigned* __restrict__ grp_base, const ull* __restrict__ headmask,
             const float* __restrict__ ea,
             float* __restrict__ out_src, float* __restrict__ out_dst,
             float* __restrict__ out_ea) {
  int w = (blockIdx.x * blockDim.x + threadIdx.x) >> 6;
  int nw = (gridDim.x * blockDim.x) >> 6;
  int lane = threadIdx.x & 63;
  int cnt = (int)hdr[9];
  for (int bi = w; bi < cnt; bi += nw) {
    int b = nb_small[bi];
    unsigned o0 = cs_off[b];
    int len = (int)(cs_off[b + 1] - o0);
    ull M = headmask[bi];
    unsigned cdv = 0xFFFFFFFFu, eidv = 0u;
    if (lane < len) {
      ull key = __builtin_nontemporal_load(&keys[o0 + lane]);
      cdv = (unsigned)(key >> 22);
      eidv = (unsigned)(key & 0x3FFFFFULL);
    }
    float4 v0 = make_float4(0.f, 0.f, 0.f, 0.f), v1 = v0;
    if (lane < len) {
      const float4* p = (const float4*)&ea[(size_t)eidv * FEA];
      v0 = p[0]; v1 = p[1];
    }
    bool head = (M >> lane) & 1ULL;
    bool allsingle = ((int)__popcll(M) == len);
    unsigned r = 0;
    for (int j = 0; j < len; ++j) {
      unsigned cj = (unsigned)__builtin_amdgcn_readlane((int)cdv, j);
      if (((M >> j) & 1ULL) && cj < cdv) r++;
    }
    float4 a0 = v0, a1 = v1;
    if (!allsingle) {
      for (int j = 0; j < len; ++j) {
        unsigned cj = (unsigned)__builtin_amdgcn_readlane((int)cdv, j);
        bool take = (cj == cdv) && (j != lane);
        float t0 = __shfl(v0.x, j), t1 = __shfl(v0.y, j);
        float t2 = __shfl(v0.z, j), t3 = __shfl(v0.w, j);
        float t4 = __shfl(v1.x, j), t5 = __shfl(v1.y, j);
        float t6 = __shfl(v1.z, j), t7 = __shfl(v1.w, j);
        if (take) {
          a0.x += t0; a0.y += t1; a0.z += t2; a0.w += t3;
          a1.x += t4; a1.y += t5; a1.z += t6; a1.w += t7;
        }
      }
    }
    if (head) {
      unsigned row = grp_base[b] + r;
      out_src[row] = (float)b;
      out_dst[row] = (float)cdv;
      float4* o = (float4*)&out_ea[(size_t)row * FEA];
      o[0] = a0; o[1] = a1;
    }
  }
}

__global__ void __launch_bounds__(256)
sort_big_k(ull* __restrict__ keys, const unsigned* __restrict__ cs_off,
           const int* __restrict__ nb_big, const unsigned* __restrict__ hdr,
           unsigned* __restrict__ grp_cnt) {
  __shared__ ull sm[LCAP];
  __shared__ ull rb[256];
  __shared__ int ri[256];
  __shared__ unsigned s4[4];
  int nbig = (int)hdr[10];
  for (int bi = blockIdx.x; bi < nbig; bi += gridDim.x) {
    int b = nb_big[bi];
    unsigned o0 = cs_off[b];
    int len = (int)(cs_off[b + 1] - o0);
    if (len <= LCAP) {
      int np = 1; while (np < len) np <<= 1;
      for (int i = threadIdx.x; i < np; i += 256)
        sm[i] = (i < len) ? keys[o0 + i] : ~0ULL;
      __syncthreads();
      for (int k = 2; k <= np; k <<= 1) {
        for (int j = k >> 1; j > 0; j >>= 1) {
          for (int i = threadIdx.x; i < np; i += 256) {
            int ixj = i ^ j;
            if (ixj > i) {
              ull a = sm[i], c = sm[ixj];
              bool up = ((i & k) == 0);
              if (up ? (a > c) : (a < c)) { sm[i] = c; sm[ixj] = a; }
            }
          }
          __syncthreads();
        }
      }
      unsigned g = 0;
      for (int i = threadIdx.x; i < len; i += 256) {
        ull kk = sm[i];
        keys[o0 + i] = kk;
        unsigned cd = (unsigned)(kk >> 22);
        if (i == 0 || (unsigned)(sm[i - 1] >> 22) != cd) g++;
      }
      for (int o = 32; o > 0; o >>= 1) g += __shfl_down(g, o);
      if ((threadIdx.x & 63) == 0) s4[threadIdx.x >> 6] = g;
      __syncthreads();
      if (threadIdx.x == 0) grp_cnt[b] = s4[0] + s4[1] + s4[2] + s4[3];
      __syncthreads();
    } else {
      for (int p = 0; p < len - 1; p++) {
        ull best = ~0ULL; int bidx = -1;
        for (int i = p + threadIdx.x; i < len; i += 256) {
          ull v = keys[o0 + i];
          if (v < best) { best = v; bidx = i; }
        }
        rb[threadIdx.x] = best; ri[threadIdx.x] = bidx;
        __syncthreads();
        for (int sd = 128; sd > 0; sd >>= 1) {
          if (threadIdx.x < sd && rb[threadIdx.x + sd] < rb[threadIdx.x]) {
            rb[threadIdx.x] = rb[threadIdx.x + sd]; ri[threadIdx.x] = ri[threadIdx.x + sd];
          }
          __syncthreads();
        }
        if (threadIdx.x == 0) {
          int m = ri[0];
          ull tmp = keys[o0 + p];
          keys[o0 + p] = rb[0];
          keys[o0 + m] = tmp;
        }
        __syncthreads();
      }
      unsigned g = 0;
      for (int i = threadIdx.x; i < len; i += 256) {
        unsigned cd = (unsigned)(keys[o0 + i] >> 22);
        if (i == 0 || (unsigned)(keys[o0 + i - 1] >> 22) != cd) g++;
      }
      for (int o = 32; o > 0; o >>= 1) g += __shfl_down(g, o);
      if ((threadIdx.x & 63) == 0) s4[threadIdx.x >> 6] = g;
      __syncthreads();
      if (threadIdx.x == 0) grp_cnt[b] = s4[0] + s4[1] + s4[2] + s4[3];
      __syncthreads();
    }
  }
}

__global__ void __launch_bounds__(256)
emit_big_k(const ull* __restrict__ keys, const unsigned* __restrict__ cs_off,
           const int* __restrict__ nb_big, const unsigned* __restrict__ hdr,
           const unsigned* __restrict__ grp_base, const float* __restrict__ ea,
           float* __restrict__ out_src, float* __restrict__ out_dst,
           float* __restrict__ out_ea) {
  __shared__ unsigned sc[256];
  __shared__ unsigned s_carry;
  int nbig = (int)hdr[10];
  for (int bi = blockIdx.x; bi < nbig; bi += gridDim.x) {
    int b = nb_big[bi];
    unsigned o0 = cs_off[b];
    int len = (int)(cs_off[b + 1] - o0);
    unsigned base = grp_base[b];
    if (threadIdx.x == 0) s_carry = 0;
    __syncthreads();
    for (int c0 = 0; c0 < len; c0 += 256) {
      int i = c0 + threadIdx.x;
      unsigned cd = 0; bool newg = false;
      if (i < len) {
        ull kk = keys[o0 + i];
        cd = (unsigned)(kk >> 22);
        newg = (i == 0) || ((unsigned)(keys[o0 + i - 1] >> 22) != cd);
      }
      unsigned flag = newg ? 1u : 0u;
      sc[threadIdx.x] = flag;
      __syncthreads();
      unsigned xv = flag;
      for (int o = 1; o < 256; o <<= 1) {
        unsigned y = (threadIdx.x >= o) ? sc[threadIdx.x - o] : 0u;
        __syncthreads();
        xv += y;
        sc[threadIdx.x] = xv;
        __syncthreads();
      }
      unsigned carry_old = s_carry;
      if (newg) {
        float a0=0,a1=0,a2=0,a3=0,a4=0,a5=0,a6=0,a7=0;
        int j = i;
        while (j < len) {
          ull k2 = keys[o0 + j];
          if ((unsigned)(k2 >> 22) != cd) break;
          unsigned eid = (unsigned)(k2 & 0x3FFFFFULL);
          const float* p = &ea[(size_t)eid * FEA];
          a0+=p[0];a1+=p[1];a2+=p[2];a3+=p[3];a4+=p[4];a5+=p[5];a6+=p[6];a7+=p[7];
          j++;
        }
        unsigned row = base + carry_old + xv - 1u;
        out_src[row] = (float)b;
        out_dst[row] = (float)cd;
        float* q = &out_ea[(size_t)row * FEA];
        q[0]=a0;q[1]=a1;q[2]=a2;q[3]=a3;q[4]=a4;q[5]=a5;q[6]=a6;q[7]=a7;
      }
      __syncthreads();
      if (threadIdx.x == 255) s_carry = carry_old + xv;
      __syncthreads();
    }
  }
}

// rows >= T (total groups) get -1/-1 and zero ea (exact-range grid-stride)
__global__ void tail_fill_k(const unsigned* __restrict__ grp_base,
                            float* __restrict__ out_src, float* __restrict__ out_dst,
                            float* __restrict__ out_ea) {
  int T = (int)grp_base[NN];
  for (int t = T + blockIdx.x * blockDim.x + threadIdx.x; t < EE;
       t += gridDim.x * blockDim.x) {
    out_src[t] = -1.0f;
    out_dst[t] = -1.0f;
    float4 z = make_float4(0.f, 0.f, 0.f, 0.f);
    float4* o = (float4*)&out_ea[(size_t)t * FEA];
    o[0] = z; o[1] = z;
  }
}

extern "C" void kernel_launch(void* const* d_in, const int* in_sizes, int n_in,
                              void* d_out, int out_size, void* d_ws, size_t ws_size,
                              hipStream_t stream) {
  const float* x   = (const float*)d_in[0];
  const float* pos = (const float*)d_in[1];
  const int* batch = (const int*)d_in[2];
  const int* ei    = (const int*)d_in[3];
  const float* ea  = (const float*)d_in[4];
  float* out = (float*)d_out;

  const size_t OX = 0;
  const size_t OP = (size_t)NN * FF;
  const size_t OB = OP + (size_t)NN * 3;
  const size_t OE = OB + (size_t)NN;
  const size_t OA = OE + (size_t)2 * EE;

  char* w = (char*)d_ws;
  size_t woff = 0;
  auto alloc = [&](size_t bytes) -> void* {
    void* p = w + woff;
    woff += (bytes + 255) & ~(size_t)255;
    return p;
  };
  // zeroed region (one memset)
  unsigned* rank    = (unsigned*)alloc((size_t)RAWCAP * 4);     // reuse: nb_big
  unsigned* cnt     = (unsigned*)alloc((size_t)(NN + 1) * 4);   // reuse: nb_small
  unsigned* node_fill = (unsigned*)alloc((size_t)NN * 4);
  unsigned* cs_cnt  = (unsigned*)alloc((size_t)(NN + 1) * 4);
  unsigned* cs_fill = (unsigned*)alloc((size_t)(NN + 1) * 4);
  unsigned* grp_cnt = (unsigned*)alloc((size_t)(NN + 1) * 4);
  ull* desc0        = (ull*)alloc(512 * 8);
  ull* desc1        = (ull*)alloc(512 * 8);
  ull* desc2        = (ull*)alloc(512 * 8);
  ull* desc3        = (ull*)alloc(512 * 8);
  size_t zero_bytes = woff;
  // written-before-read region
  int* cluster      = (int*)alloc((size_t)NN * 4);
  int* nlist        = (int*)alloc((size_t)NN * 4);
  unsigned* node_off= (unsigned*)alloc((size_t)(NN + 2) * 4);
  unsigned* cs_off  = (unsigned*)alloc((size_t)(NN + 2) * 4);
  unsigned* grp_base= (unsigned*)alloc((size_t)(NN + 2) * 4);
  unsigned* hdr     = (unsigned*)alloc(256);
  ull* headmask     = (ull*)alloc((size_t)NN * 8);
  ull* keys         = (ull*)alloc((size_t)EE * 8);
  ull* erec         = (ull*)alloc((size_t)EE * 8);   // one-atomic-pass staging
  bool twopass = (ws_size >= woff);

  int* nb_small = (int*)cnt;    // dead after node_off scan
  int* nb_big   = (int*)rank;   // dead after node_cnt_k

  hipMemsetAsync(d_ws, 0, zero_bytes, stream);

  init_hdr_k<<<1, 64, 0, stream>>>(hdr);
  minmax_k<<<128, 256, 0, stream>>>(pos, hdr);
  dims_k<<<1, 64, 0, stream>>>(hdr);
  raw_k<<<(NN + 255) / 256, 256, 0, stream>>>(pos, batch, hdr, cluster, rank);

  auto scan1 = [&](const unsigned* in_, unsigned* out_, int ntot,
                   unsigned* total_out, ull* d_) {
    int nb = (ntot + 1023) / 1024;
    scan_lb_k<<<nb, 256, 0, stream>>>(in_, out_, ntot, total_out, d_, nb);
  };
  scan1(rank, rank, RAWCAP, hdr + 8, desc0);   // rank[raw] = cluster id; total -> ncl

  node_cnt_k<<<(NN + 255) / 256, 256, 0, stream>>>(rank, cluster, cnt);
  scan1(cnt, node_off, NN + 1, nullptr, desc1);
  node_scatter_k<<<(NN + 255) / 256, 256, 0, stream>>>(cluster, node_off, node_fill, nlist);
  cluster_reduce_k<<<2048, 256, 0, stream>>>(x, pos, batch, nlist, node_off, hdr,
                                             out + OX, out + OP, out + OB);
  node_tail_k<<<2048, 256, 0, stream>>>(hdr, out + OX, out + OP, out + OB);

  if (twopass) {
    edge_cnt_pair_k<<<(EE + 255) / 256, 256, 0, stream>>>(ei, cluster, cs_cnt, erec);
  } else {
    edge_cnt_k<<<(EE + 255) / 256, 256, 0, stream>>>(ei, cluster, cs_cnt);
  }
  scan1(cs_cnt, cs_off, NN + 1, nullptr, desc2);
  if (twopass) {
    edge_place_k<<<2048, 256, 0, stream>>>(erec, cs_off, keys);
  } else {
    edge_scatter_k<<<(EE + 255) / 256, 256, 0, stream>>>(ei, cluster, cs_off, cs_fill, keys);
  }

  compact_k<<<(NN + 255) / 256, 256, 0, stream>>>(cs_off, hdr, nb_small, nb_big);
  group_small_k<<<2048, 256, 0, stream>>>(keys, cs_off, nb_small, hdr, grp_cnt, headmask);
  sort_big_k<<<256, 256, 0, stream>>>(keys, cs_off, nb_big, hdr, grp_cnt);
  scan1(grp_cnt, grp_base, NN + 1, nullptr, desc3);
  emit_small_k<<<4096, 256, 0, stream>>>(keys, cs_off, nb_small, hdr, grp_base, headmask, ea,
                                         out + OE, out + OE + EE, out + OA);
  emit_big_k<<<256, 256, 0, stream>>>(keys, cs_off, nb_big, hdr, grp_base, ea,
                                      out + OE, out + OE + EE, out + OA);
  tail_fill_k<<<512, 256, 0, stream>>>(grp_base, out + OE, out + OE + EE, out + OA);
}

// Round 10
// 560.423 us; speedup vs baseline: 1.2169x; 1.1961x over previous
//
#include <hip/hip_runtime.h>

#define NN 300000
#define FF 64
#define EE 2400000
#define FEA 8
#define RAWCAP 131072   // >= 8*129*97 = 100104 (so cluster ids < 2^17)
#define NBUCK 2048      // coarse buckets: cb = cs>>6, cs < 2^17
#define NSB 512         // scatter blocks
#define TILE ((EE + NSB - 1) / NSB)   // 4688 edges per scatter block
#define CAP 2560        // max bucket len for LDS sort (mean ~1650, +22 sigma)

typedef unsigned long long ull;

__device__ __forceinline__ unsigned fenc(float f) {
  unsigned b = __float_as_uint(f);
  return (b & 0x80000000u) ? ~b : (b | 0x80000000u);
}
__device__ __forceinline__ float fdec(unsigned e) {
  unsigned b = (e & 0x80000000u) ? (e ^ 0x80000000u) : ~e;
  return __uint_as_float(b);
}

__global__ void init_hdr_k(unsigned* hdr) {
  if (threadIdx.x == 0) {
    hdr[0] = 0xFFFFFFFFu; hdr[1] = 0xFFFFFFFFu;  // min enc
    hdr[2] = 0u;          hdr[3] = 0u;           // max enc
  }
}

__global__ void minmax_k(const float* __restrict__ pos, unsigned* hdr) {
  __shared__ unsigned red[4][4];
  int t = blockIdx.x * blockDim.x + threadIdx.x;
  float mnx = 1e30f, mny = 1e30f, mxx = -1e30f, mxy = -1e30f;
  for (int i = t; i < NN; i += gridDim.x * blockDim.x) {
    float px = pos[i * 3 + 1], py = pos[i * 3 + 2];
    mnx = fminf(mnx, px); mny = fminf(mny, py);
    mxx = fmaxf(mxx, px); mxy = fmaxf(mxy, py);
  }
  for (int o = 1; o < 64; o <<= 1) {
    mnx = fminf(mnx, __shfl_xor(mnx, o));
    mny = fminf(mny, __shfl_xor(mny, o));
    mxx = fmaxf(mxx, __shfl_xor(mxx, o));
    mxy = fmaxf(mxy, __shfl_xor(mxy, o));
  }
  int wid = threadIdx.x >> 6;
  if ((threadIdx.x & 63) == 0) {
    red[wid][0] = fenc(mnx); red[wid][1] = fenc(mny);
    red[wid][2] = fenc(mxx); red[wid][3] = fenc(mxy);
  }
  __syncthreads();
  if (threadIdx.x == 0) {
    unsigned a0 = red[0][0], a1 = red[0][1], a2 = red[0][2], a3 = red[0][3];
    for (int k = 1; k < 4; k++) {
      a0 = min(a0, red[k][0]); a1 = min(a1, red[k][1]);
      a2 = max(a2, red[k][2]); a3 = max(a3, red[k][3]);
    }
    atomicMin(&hdr[0], a0); atomicMin(&hdr[1], a1);
    atomicMax(&hdr[2], a2); atomicMax(&hdr[3], a3);
  }
}

__global__ void dims_k(unsigned* hdr) {
  if (threadIdx.x == 0 && blockIdx.x == 0) {
    float mnx = fdec(hdr[0]), mny = fdec(hdr[1]);
    float mxx = fdec(hdr[2]), mxy = fdec(hdr[3]);
    int d0 = (int)(floorf((mxx - mnx) / 5.0f) + 1.0f);
    int d1 = (int)(floorf((mxy - mny) / 5.0f) + 1.0f);
    hdr[4] = (unsigned)d0;
    hdr[5] = (unsigned)d1;
    ((float*)hdr)[6] = mnx;
    ((float*)hdr)[7] = mny;
  }
}

__global__ void raw_k(const float* __restrict__ pos, const int* __restrict__ batch,
                      const unsigned* __restrict__ hdr, int* __restrict__ cluster,
                      unsigned* __restrict__ flags) {
  int i = blockIdx.x * blockDim.x + threadIdx.x;
  if (i >= NN) return;
  float mnx = ((const float*)hdr)[6], mny = ((const float*)hdr)[7];
  int d0 = (int)hdr[4], d1 = (int)hdr[5];
  int c0 = (int)floorf((pos[i * 3 + 1] - mnx) / 5.0f);
  int c1 = (int)floorf((pos[i * 3 + 2] - mny) / 5.0f);
  int raw = batch[i] * (d0 * d1) + c0 * d1 + c1;
  cluster[i] = raw;
  flags[raw] = 1u;
}

// single-kernel exclusive scan: decoupled lookback (validated r8/r9).
// in-place safe (each element read+written by same thread only).
__global__ void __launch_bounds__(256)
scan_lb_k(const unsigned* __restrict__ in, unsigned* __restrict__ out, int ntot,
          unsigned* __restrict__ total_out, ull* __restrict__ desc, int nb) {
  __shared__ unsigned sc[256];
  __shared__ unsigned s_pref;
  int bid = blockIdx.x;
  int base = bid * 1024 + threadIdx.x * 4;
  unsigned v[4]; unsigned s = 0;
#pragma unroll
  for (int k = 0; k < 4; k++) {
    int i = base + k;
    v[k] = (i < ntot) ? in[i] : 0u;
    s += v[k];
  }
  sc[threadIdx.x] = s;
  __syncthreads();
  unsigned xv = s;
  for (int o = 1; o < 256; o <<= 1) {
    unsigned y = (threadIdx.x >= o) ? sc[threadIdx.x - o] : 0u;
    __syncthreads();
    xv += y;
    sc[threadIdx.x] = xv;
    __syncthreads();
  }
  unsigned btot = sc[255];
  if (threadIdx.x == 0) {
    unsigned ex = 0;
    if (bid == 0) {
      atomicExch(&desc[0], (2ULL << 32) | (ull)btot);
    } else {
      atomicExch(&desc[bid], (1ULL << 32) | (ull)btot);
      int p = bid - 1;
      while (true) {
        ull d = atomicAdd(&desc[p], 0ULL);
        unsigned fl = (unsigned)(d >> 32);
        if (fl == 2u) { ex += (unsigned)d; break; }
        if (fl == 1u) { ex += (unsigned)d; --p; }
      }
      atomicExch(&desc[bid], (2ULL << 32) | (ull)(ex + btot));
    }
    s_pref = ex;
    if (total_out && bid == nb - 1) *total_out = ex + btot;
  }
  __syncthreads();
  unsigned run = s_pref + xv - s;
#pragma unroll
  for (int k = 0; k < 4; k++) {
    int i = base + k;
    if (i < ntot) out[i] = run;
    run += v[k];
  }
}

// map raw->cluster id, count members, pack slot r into cluster: (r<<17)|cl
__global__ void node_cnt_k(const unsigned* __restrict__ rank, int* __restrict__ cluster,
                           unsigned* __restrict__ cnt) {
  int i = blockIdx.x * blockDim.x + threadIdx.x;
  if (i >= NN) return;
  unsigned cl = rank[cluster[i]];
  unsigned r = atomicAdd(&cnt[cl], 1u);
  cluster[i] = (int)((r << 17) | cl);
}

// atomic-free: position = node_off[cl] + packed slot
__global__ void node_scatter_k(const int* __restrict__ cluster,
                               const unsigned* __restrict__ node_off,
                               int* __restrict__ nlist) {
  int i = blockIdx.x * blockDim.x + threadIdx.x;
  if (i >= NN) return;
  unsigned c = (unsigned)cluster[i];
  nlist[node_off[c & 0x1FFFFu] + (c >> 17)] = i;
}

// one wave per cluster: gather member rows, fmax in registers, write once.
__global__ void __launch_bounds__(256)
cluster_reduce_k(const float* __restrict__ x, const float* __restrict__ pos,
                 const int* __restrict__ batch, const int* __restrict__ nlist,
                 const unsigned* __restrict__ node_off, const unsigned* __restrict__ hdr,
                 float* __restrict__ out_x, float* __restrict__ out_pos,
                 float* __restrict__ out_batch) {
  int w = (blockIdx.x * blockDim.x + threadIdx.x) >> 6;
  int nw = (gridDim.x * blockDim.x) >> 6;
  int f = threadIdx.x & 63;
  int ncl = (int)hdr[8];
  for (int c = w; c < ncl; c += nw) {
    unsigned o0 = node_off[c];
    int len = (int)(node_off[c + 1] - o0);
    float mx = -1e38f;
    long long ps = 0;
    for (int m = 0; m < len; m++) {
      int nd = nlist[o0 + m];
      mx = fmaxf(mx, x[(size_t)nd * FF + f]);
      if (f < 3) ps += (long long)llrintf(pos[nd * 3 + f] * 65536.0f);
    }
    out_x[(size_t)c * FF + f] = mx;
    if (f < 3) {
      float v = (float)((double)ps / 65536.0 / (double)len);
      if (f > 0) v = floorf(v / 4.0f);
      out_pos[c * 3 + f] = v;
    }
    if (f == 63) out_batch[c] = (float)batch[nlist[o0]];
  }
}

__global__ void node_tail_k(const unsigned* __restrict__ hdr,
                            float* __restrict__ out_x, float* __restrict__ out_pos,
                            float* __restrict__ out_batch) {
  int ncl = (int)hdr[8];
  int total = (NN - ncl) * FF;
  for (int i = blockIdx.x * blockDim.x + threadIdx.x; i < total;
       i += gridDim.x * blockDim.x) {
    int r = ncl + (i >> 6), f = i & 63;
    out_x[(size_t)r * FF + f] = 0.0f;
    if (f < 3) out_pos[r * 3 + f] = 0.0f;
    if (f == 0) out_batch[r] = -1.0f;
  }
}

// ---- edge pipeline: MSD coarse partition + per-bucket LDS sort ----

// per-block histogram over 2048 coarse buckets; mat[blk][cb] (blk-major, seq write)
__global__ void __launch_bounds__(256)
coarse_cnt_k(const int* __restrict__ ei, const int* __restrict__ cluster,
             unsigned* __restrict__ mat) {
  __shared__ unsigned h[NBUCK];
  for (int i = threadIdx.x; i < NBUCK; i += 256) h[i] = 0u;
  __syncthreads();
  int t0 = blockIdx.x * TILE;
  for (int k = threadIdx.x; k < TILE; k += 256) {
    int t = t0 + k;
    if (t >= EE) break;
    unsigned s = (unsigned)cluster[ei[t]] & 0x1FFFFu;
    unsigned d = (unsigned)cluster[ei[EE + t]] & 0x1FFFFu;
    if (s != d) atomicAdd(&h[s >> 6], 1u);
  }
  __syncthreads();
  for (int i = threadIdx.x; i < NBUCK; i += 256)
    mat[(size_t)blockIdx.x * NBUCK + i] = h[i];
}

// transpose to cb-major for the scan: matT[cb*NSB+blk] = mat[blk*NBUCK+cb]
__global__ void transpose_k(const unsigned* __restrict__ mat, unsigned* __restrict__ matT) {
  int f = blockIdx.x * blockDim.x + threadIdx.x;
  if (f >= NSB * NBUCK) return;
  int cb = f / NSB, blk = f - cb * NSB;
  matT[f] = mat[(size_t)blk * NBUCK + cb];
}

// scatter: each (block,bucket) chunk is single-writer contiguous (no global atomics)
__global__ void __launch_bounds__(256)
coarse_scatter_k(const int* __restrict__ ei, const int* __restrict__ cluster,
                 const unsigned* __restrict__ matT, ull* __restrict__ keys) {
  __shared__ unsigned cur[NBUCK];
  for (int i = threadIdx.x; i < NBUCK; i += 256)
    cur[i] = matT[(size_t)i * NSB + blockIdx.x];
  __syncthreads();
  int t0 = blockIdx.x * TILE;
  for (int k = threadIdx.x; k < TILE; k += 256) {
    int t = t0 + k;
    if (t >= EE) break;
    unsigned s = (unsigned)cluster[ei[t]] & 0x1FFFFu;
    unsigned d = (unsigned)cluster[ei[EE + t]] & 0x1FFFFu;
    if (s == d) continue;
    unsigned p = atomicAdd(&cur[s >> 6], 1u);
    ull key23 = ((ull)(s & 63u) << 17) | d;      // (cs_low6, cd)
    keys[p] = (key23 << 22) | (unsigned)t;        // | eid
  }
}

// one block per coarse bucket: 12x4-bit LDS radix over full 45-bit key
// (unique keys -> deterministic order), then group count.
__global__ void __launch_bounds__(256)
bucket_sort_k(ull* __restrict__ keys, const unsigned* __restrict__ matT,
              const unsigned* __restrict__ hdr, unsigned* __restrict__ grp_cnt) {
  __shared__ ull buf0[CAP];
  __shared__ ull buf1[CAP];
  __shared__ unsigned mat16[4096];
  __shared__ unsigned sc[256];
  int cb = blockIdx.x;
  unsigned start = matT[(size_t)cb * NSB];
  unsigned end = (cb == NBUCK - 1) ? hdr[11] : matT[(size_t)(cb + 1) * NSB];
  int len = (int)(end - start);
  if (len <= 0) { if (threadIdx.x == 0) grp_cnt[cb] = 0u; return; }
  int tid = threadIdx.x;
  if (len <= CAP) {
    for (int i = tid; i < len; i += 256) buf0[i] = keys[start + i];
    __syncthreads();
    int K = (len + 255) >> 8;
    int lo = tid * K, hi = min(lo + K, len);
    if (lo > len) lo = len;
#pragma unroll 1
    for (int p = 0; p < 12; p++) {
      ull* src = (p & 1) ? buf1 : buf0;
      ull* dst = (p & 1) ? buf0 : buf1;
      int sh = 4 * p;
      unsigned c16[16];
#pragma unroll
      for (int d = 0; d < 16; d++) c16[d] = 0u;
      for (int i = lo; i < hi; i++)
        c16[(unsigned)(src[i] >> sh) & 15u]++;
#pragma unroll
      for (int d = 0; d < 16; d++) mat16[d * 256 + tid] = c16[d];
      __syncthreads();
      unsigned ps = 0;
#pragma unroll
      for (int j = 0; j < 16; j++) ps += mat16[tid * 16 + j];
      sc[tid] = ps;
      __syncthreads();
      unsigned xv = ps;
      for (int o = 1; o < 256; o <<= 1) {
        unsigned y = (tid >= o) ? sc[tid - o] : 0u;
        __syncthreads();
        xv += y;
        sc[tid] = xv;
        __syncthreads();
      }
      unsigned run = xv - ps;
#pragma unroll
      for (int j = 0; j < 16; j++) {
        unsigned tmp = mat16[tid * 16 + j];
        mat16[tid * 16 + j] = run;
        run += tmp;
      }
      __syncthreads();
      unsigned cur16[16];
#pragma unroll
      for (int d = 0; d < 16; d++) cur16[d] = mat16[d * 256 + tid];
      for (int i = lo; i < hi; i++) {
        ull v = src[i];
        unsigned d = (unsigned)(v >> sh) & 15u;
        dst[cur16[d]++] = v;
      }
      __syncthreads();
    }
    // result in buf0 (12 passes)
    unsigned g = 0;
    for (int i = lo; i < hi; i++) {
      if (i == 0 || (unsigned)(buf0[i] >> 22) != (unsigned)(buf0[i - 1] >> 22)) g++;
    }
    sc[tid] = g;
    __syncthreads();
    for (int sd = 128; sd > 0; sd >>= 1) {
      if (tid < sd) sc[tid] += sc[tid + sd];
      __syncthreads();
    }
    if (tid == 0) grp_cnt[cb] = sc[0];
    for (int i = tid; i < len; i += 256) keys[start + i] = buf0[i];
  } else {
    // insurance path (unreachable for this data): global selection sort
    ull* rb = buf0;
    int* ri = (int*)mat16;
    for (int p = 0; p < len - 1; p++) {
      ull best = ~0ULL; int bidx = -1;
      for (int i = p + tid; i < len; i += 256) {
        ull v = keys[start + i];
        if (v < best) { best = v; bidx = i; }
      }
      rb[tid] = best; ri[tid] = bidx;
      __syncthreads();
      for (int sd = 128; sd > 0; sd >>= 1) {
        if (tid < sd && rb[tid + sd] < rb[tid]) {
          rb[tid] = rb[tid + sd]; ri[tid] = ri[tid + sd];
        }
        __syncthreads();
      }
      if (tid == 0) {
        int m = ri[0];
        ull tmp = keys[start + p];
        keys[start + p] = rb[0];
        keys[start + m] = tmp;
      }
      __syncthreads();
    }
    unsigned g = 0;
    for (int i = tid; i < len; i += 256) {
      unsigned cd = (unsigned)(keys[start + i] >> 22);
      if (i == 0 || (unsigned)(keys[start + i - 1] >> 22) != cd) g++;
    }
    sc[tid] = 0;
    __syncthreads();
    sc[tid] = g;
    __syncthreads();
    for (int sd = 128; sd > 0; sd >>= 1) {
      if (tid < sd) sc[tid] += sc[tid + sd];
      __syncthreads();
    }
    if (tid == 0) grp_cnt[cb] = sc[0];
  }
}

// one block per bucket: heads + ranks via block scan; rows sequential; ea gather
__global__ void __launch_bounds__(256)
bucket_emit_k(const ull* __restrict__ keys, const unsigned* __restrict__ matT,
              const unsigned* __restrict__ hdr, const unsigned* __restrict__ grp_base,
              const float* __restrict__ ea,
              float* __restrict__ out_src, float* __restrict__ out_dst,
              float* __restrict__ out_ea) {
  __shared__ ull buf[CAP];
  __shared__ unsigned sc[256];
  int cb = blockIdx.x;
  unsigned start = matT[(size_t)cb * NSB];
  unsigned end = (cb == NBUCK - 1) ? hdr[11] : matT[(size_t)(cb + 1) * NSB];
  int len = (int)(end - start);
  if (len <= 0) return;
  int tid = threadIdx.x;
  bool lds = (len <= CAP);
  if (lds) {
    for (int i = tid; i < len; i += 256) buf[i] = keys[start + i];
    __syncthreads();
  }
  unsigned base = grp_base[cb];
  int K = (len + 255) >> 8;
  int lo = tid * K, hi = min(lo + K, len);
  if (lo > len) lo = len;
  unsigned g = 0;
  for (int i = lo; i < hi; i++) {
    ull v = lds ? buf[i] : keys[start + i];
    ull pv = (i == 0) ? ~0ULL : (lds ? buf[i - 1] : keys[start + i - 1]);
    if (i == 0 || (unsigned)(v >> 22) != (unsigned)(pv >> 22)) g++;
  }
  sc[tid] = g;
  __syncthreads();
  unsigned xv = g;
  for (int o = 1; o < 256; o <<= 1) {
    unsigned y = (tid >= o) ? sc[tid - o] : 0u;
    __syncthreads();
    xv += y;
    sc[tid] = xv;
    __syncthreads();
  }
  unsigned rank = base + xv - g;
  for (int i = lo; i < hi; i++) {
    ull v = lds ? buf[i] : keys[start + i];
    unsigned k23 = (unsigned)(v >> 22);
    ull pv = (i == 0) ? ~0ULL : (lds ? buf[i - 1] : keys[start + i - 1]);
    bool head = (i == 0) || ((unsigned)(pv >> 22) != k23);
    if (!head) continue;
    unsigned eid = (unsigned)(v & 0x3FFFFFULL);
    const float4* p = (const float4*)&ea[(size_t)eid * FEA];
    float4 a0 = p[0], a1 = p[1];
    int j = i + 1;
    while (j < len) {
      ull v2 = lds ? buf[j] : keys[start + j];
      if ((unsigned)(v2 >> 22) != k23) break;
      const float4* q = (const float4*)&ea[(size_t)(v2 & 0x3FFFFFULL) * FEA];
      float4 b0 = q[0], b1 = q[1];
      a0.x += b0.x; a0.y += b0.y; a0.z += b0.z; a0.w += b0.w;
      a1.x += b1.x; a1.y += b1.y; a1.z += b1.z; a1.w += b1.w;
      j++;
    }
    unsigned cs = ((unsigned)cb << 6) | (k23 >> 17);
    out_src[rank] = (float)cs;
    out_dst[rank] = (float)(k23 & 0x1FFFFu);
    float4* o = (float4*)&out_ea[(size_t)rank * FEA];
    o[0] = a0; o[1] = a1;
    rank++;
  }
}

// rows >= T get -1/-1 and zero ea
__global__ void tail_fill_k(const unsigned* __restrict__ grp_base,
                            float* __restrict__ out_src, float* __restrict__ out_dst,
                            float* __restrict__ out_ea) {
  int T = (int)grp_base[NBUCK];
  for (int t = T + blockIdx.x * blockDim.x + threadIdx.x; t < EE;
       t += gridDim.x * blockDim.x) {
    out_src[t] = -1.0f;
    out_dst[t] = -1.0f;
    float4 z = make_float4(0.f, 0.f, 0.f, 0.f);
    float4* o = (float4*)&out_ea[(size_t)t * FEA];
    o[0] = z; o[1] = z;
  }
}

extern "C" void kernel_launch(void* const* d_in, const int* in_sizes, int n_in,
                              void* d_out, int out_size, void* d_ws, size_t ws_size,
                              hipStream_t stream) {
  const float* x   = (const float*)d_in[0];
  const float* pos = (const float*)d_in[1];
  const int* batch = (const int*)d_in[2];
  const int* ei    = (const int*)d_in[3];
  const float* ea  = (const float*)d_in[4];
  float* out = (float*)d_out;

  const size_t OX = 0;
  const size_t OP = (size_t)NN * FF;
  const size_t OB = OP + (size_t)NN * 3;
  const size_t OE = OB + (size_t)NN;
  const size_t OA = OE + (size_t)2 * EE;

  char* w = (char*)d_ws;
  size_t woff = 0;
  auto alloc = [&](size_t bytes) -> void* {
    void* p = w + woff;
    woff += (bytes + 255) & ~(size_t)255;
    return p;
  };
  // zeroed region (one memset)
  unsigned* rank    = (unsigned*)alloc((size_t)RAWCAP * 4);
  unsigned* cnt     = (unsigned*)alloc((size_t)(NN + 1) * 4);
  unsigned* grp_cnt = (unsigned*)alloc((size_t)(NBUCK + 1) * 4);
  ull* desc0        = (ull*)alloc(2048 * 8);
  ull* desc1        = (ull*)alloc(2048 * 8);
  ull* desc2        = (ull*)alloc(2048 * 8);
  ull* desc3        = (ull*)alloc(2048 * 8);
  size_t zero_bytes = woff;
  // written-before-read region
  int* cluster      = (int*)alloc((size_t)NN * 4);
  int* nlist        = (int*)alloc((size_t)NN * 4);
  unsigned* node_off= (unsigned*)alloc((size_t)(NN + 2) * 4);
  unsigned* mat     = (unsigned*)alloc((size_t)NSB * NBUCK * 4);
  unsigned* matT    = (unsigned*)alloc((size_t)NSB * NBUCK * 4);
  unsigned* grp_base= (unsigned*)alloc((size_t)(NBUCK + 2) * 4);
  unsigned* hdr     = (unsigned*)alloc(256);
  ull* keys         = (ull*)alloc((size_t)EE * 8);

  hipMemsetAsync(d_ws, 0, zero_bytes, stream);

  init_hdr_k<<<1, 64, 0, stream>>>(hdr);
  minmax_k<<<128, 256, 0, stream>>>(pos, hdr);
  dims_k<<<1, 64, 0, stream>>>(hdr);
  raw_k<<<(NN + 255) / 256, 256, 0, stream>>>(pos, batch, hdr, cluster, rank);

  auto scan1 = [&](const unsigned* in_, unsigned* out_, int ntot,
                   unsigned* total_out, ull* d_) {
    int nb = (ntot + 1023) / 1024;
    scan_lb_k<<<nb, 256, 0, stream>>>(in_, out_, ntot, total_out, d_, nb);
  };
  scan1(rank, rank, RAWCAP, hdr + 8, desc0);   // rank[raw]=cluster id; total->ncl

  node_cnt_k<<<(NN + 255) / 256, 256, 0, stream>>>(rank, cluster, cnt);
  scan1(cnt, node_off, NN + 1, nullptr, desc1);
  node_scatter_k<<<(NN + 255) / 256, 256, 0, stream>>>(cluster, node_off, nlist);
  cluster_reduce_k<<<2048, 256, 0, stream>>>(x, pos, batch, nlist, node_off, hdr,
                                             out + OX, out + OP, out + OB);
  node_tail_k<<<2048, 256, 0, stream>>>(hdr, out + OX, out + OP, out + OB);

  coarse_cnt_k<<<NSB, 256, 0, stream>>>(ei, cluster, mat);
  transpose_k<<<(NSB * NBUCK + 255) / 256, 256, 0, stream>>>(mat, matT);
  scan1(matT, matT, NSB * NBUCK, hdr + 11, desc2);   // chunk offsets; total->Etot
  coarse_scatter_k<<<NSB, 256, 0, stream>>>(ei, cluster, matT, keys);
  bucket_sort_k<<<NBUCK, 256, 0, stream>>>(keys, matT, hdr, grp_cnt);
  scan1(grp_cnt, grp_base, NBUCK + 1, nullptr, desc3);
  bucket_emit_k<<<NBUCK, 256, 0, stream>>>(keys, matT, hdr, grp_base, ea,
                                           out + OE, out + OE + EE, out + OA);
  tail_fill_k<<<512, 256, 0, stream>>>(grp_base, out + OE, out + OE + EE, out + OA);
}

// Round 11
// 512.695 us; speedup vs baseline: 1.3302x; 1.0931x over previous
//
#include <hip/hip_runtime.h>

#define NN 300000
#define FF 64
#define EE 2400000
#define FEA 8
#define RAWCAP 131072   // >= 8*129*97 = 100104 (so cluster ids < 2^17)
#define NCS 131072      // cs id space (== RAWCAP)
#define NBUCK 2048      // coarse buckets: cb = cs>>6
#define NSB 512         // scatter blocks
#define TILE ((EE + NSB - 1) / NSB)
#define LCAP 2048       // big-bucket bitonic capacity

typedef unsigned long long ull;

__device__ __forceinline__ unsigned fenc(float f) {
  unsigned b = __float_as_uint(f);
  return (b & 0x80000000u) ? ~b : (b | 0x80000000u);
}
__device__ __forceinline__ float fdec(unsigned e) {
  unsigned b = (e & 0x80000000u) ? (e ^ 0x80000000u) : ~e;
  return __uint_as_float(b);
}

__global__ void init_hdr_k(unsigned* hdr) {
  if (threadIdx.x == 0) {
    hdr[0] = 0xFFFFFFFFu; hdr[1] = 0xFFFFFFFFu;  // min enc
    hdr[2] = 0u;          hdr[3] = 0u;           // max enc
    hdr[9] = 0u;          hdr[10] = 0u;          // compact-list counters
  }
}

__global__ void minmax_k(const float* __restrict__ pos, unsigned* hdr) {
  __shared__ unsigned red[4][4];
  int t = blockIdx.x * blockDim.x + threadIdx.x;
  float mnx = 1e30f, mny = 1e30f, mxx = -1e30f, mxy = -1e30f;
  for (int i = t; i < NN; i += gridDim.x * blockDim.x) {
    float px = pos[i * 3 + 1], py = pos[i * 3 + 2];
    mnx = fminf(mnx, px); mny = fminf(mny, py);
    mxx = fmaxf(mxx, px); mxy = fmaxf(mxy, py);
  }
  for (int o = 1; o < 64; o <<= 1) {
    mnx = fminf(mnx, __shfl_xor(mnx, o));
    mny = fminf(mny, __shfl_xor(mny, o));
    mxx = fmaxf(mxx, __shfl_xor(mxx, o));
    mxy = fmaxf(mxy, __shfl_xor(mxy, o));
  }
  int wid = threadIdx.x >> 6;
  if ((threadIdx.x & 63) == 0) {
    red[wid][0] = fenc(mnx); red[wid][1] = fenc(mny);
    red[wid][2] = fenc(mxx); red[wid][3] = fenc(mxy);
  }
  __syncthreads();
  if (threadIdx.x == 0) {
    unsigned a0 = red[0][0], a1 = red[0][1], a2 = red[0][2], a3 = red[0][3];
    for (int k = 1; k < 4; k++) {
      a0 = min(a0, red[k][0]); a1 = min(a1, red[k][1]);
      a2 = max(a2, red[k][2]); a3 = max(a3, red[k][3]);
    }
    atomicMin(&hdr[0], a0); atomicMin(&hdr[1], a1);
    atomicMax(&hdr[2], a2); atomicMax(&hdr[3], a3);
  }
}

__global__ void dims_k(unsigned* hdr) {
  if (threadIdx.x == 0 && blockIdx.x == 0) {
    float mnx = fdec(hdr[0]), mny = fdec(hdr[1]);
    float mxx = fdec(hdr[2]), mxy = fdec(hdr[3]);
    int d0 = (int)(floorf((mxx - mnx) / 5.0f) + 1.0f);
    int d1 = (int)(floorf((mxy - mny) / 5.0f) + 1.0f);
    hdr[4] = (unsigned)d0;
    hdr[5] = (unsigned)d1;
    ((float*)hdr)[6] = mnx;
    ((float*)hdr)[7] = mny;
  }
}

__global__ void raw_k(const float* __restrict__ pos, const int* __restrict__ batch,
                      const unsigned* __restrict__ hdr, int* __restrict__ cluster,
                      unsigned* __restrict__ flags) {
  int i = blockIdx.x * blockDim.x + threadIdx.x;
  if (i >= NN) return;
  float mnx = ((const float*)hdr)[6], mny = ((const float*)hdr)[7];
  int d0 = (int)hdr[4], d1 = (int)hdr[5];
  int c0 = (int)floorf((pos[i * 3 + 1] - mnx) / 5.0f);
  int c1 = (int)floorf((pos[i * 3 + 2] - mny) / 5.0f);
  int raw = batch[i] * (d0 * d1) + c0 * d1 + c1;
  cluster[i] = raw;
  flags[raw] = 1u;
}

// single-kernel exclusive scan: decoupled lookback (validated r8-r10)
__global__ void __launch_bounds__(256)
scan_lb_k(const unsigned* __restrict__ in, unsigned* __restrict__ out, int ntot,
          unsigned* __restrict__ total_out, ull* __restrict__ desc, int nb) {
  __shared__ unsigned sc[256];
  __shared__ unsigned s_pref;
  int bid = blockIdx.x;
  int base = bid * 1024 + threadIdx.x * 4;
  unsigned v[4]; unsigned s = 0;
#pragma unroll
  for (int k = 0; k < 4; k++) {
    int i = base + k;
    v[k] = (i < ntot) ? in[i] : 0u;
    s += v[k];
  }
  sc[threadIdx.x] = s;
  __syncthreads();
  unsigned xv = s;
  for (int o = 1; o < 256; o <<= 1) {
    unsigned y = (threadIdx.x >= o) ? sc[threadIdx.x - o] : 0u;
    __syncthreads();
    xv += y;
    sc[threadIdx.x] = xv;
    __syncthreads();
  }
  unsigned btot = sc[255];
  if (threadIdx.x == 0) {
    unsigned ex = 0;
    if (bid == 0) {
      atomicExch(&desc[0], (2ULL << 32) | (ull)btot);
    } else {
      atomicExch(&desc[bid], (1ULL << 32) | (ull)btot);
      int p = bid - 1;
      while (true) {
        ull d = atomicAdd(&desc[p], 0ULL);
        unsigned fl = (unsigned)(d >> 32);
        if (fl == 2u) { ex += (unsigned)d; break; }
        if (fl == 1u) { ex += (unsigned)d; --p; }
      }
      atomicExch(&desc[bid], (2ULL << 32) | (ull)(ex + btot));
    }
    s_pref = ex;
    if (total_out && bid == nb - 1) *total_out = ex + btot;
  }
  __syncthreads();
  unsigned run = s_pref + xv - s;
#pragma unroll
  for (int k = 0; k < 4; k++) {
    int i = base + k;
    if (i < ntot) out[i] = run;
    run += v[k];
  }
}

// map raw->cluster id, count members, pack slot r into cluster: (r<<17)|cl
__global__ void node_cnt_k(const unsigned* __restrict__ rank, int* __restrict__ cluster,
                           unsigned* __restrict__ cnt) {
  int i = blockIdx.x * blockDim.x + threadIdx.x;
  if (i >= NN) return;
  unsigned cl = rank[cluster[i]];
  unsigned r = atomicAdd(&cnt[cl], 1u);
  cluster[i] = (int)((r << 17) | cl);
}

// atomic-free: position = node_off[cl] + packed slot
__global__ void node_scatter_k(const int* __restrict__ cluster,
                               const unsigned* __restrict__ node_off,
                               int* __restrict__ nlist) {
  int i = blockIdx.x * blockDim.x + threadIdx.x;
  if (i >= NN) return;
  unsigned c = (unsigned)cluster[i];
  nlist[node_off[c & 0x1FFFFu] + (c >> 17)] = i;
}

// one wave per cluster: gather member rows, fmax in registers, write once.
__global__ void __launch_bounds__(256)
cluster_reduce_k(const float* __restrict__ x, const float* __restrict__ pos,
                 const int* __restrict__ batch, const int* __restrict__ nlist,
                 const unsigned* __restrict__ node_off, const unsigned* __restrict__ hdr,
                 float* __restrict__ out_x, float* __restrict__ out_pos,
                 float* __restrict__ out_batch) {
  int w = (blockIdx.x * blockDim.x + threadIdx.x) >> 6;
  int nw = (gridDim.x * blockDim.x) >> 6;
  int f = threadIdx.x & 63;
  int ncl = (int)hdr[8];
  for (int c = w; c < ncl; c += nw) {
    unsigned o0 = node_off[c];
    int len = (int)(node_off[c + 1] - o0);
    float mx = -1e38f;
    long long ps = 0;
    for (int m = 0; m < len; m++) {
      int nd = nlist[o0 + m];
      mx = fmaxf(mx, x[(size_t)nd * FF + f]);
      if (f < 3) ps += (long long)llrintf(pos[nd * 3 + f] * 65536.0f);
    }
    out_x[(size_t)c * FF + f] = mx;
    if (f < 3) {
      float v = (float)((double)ps / 65536.0 / (double)len);
      if (f > 0) v = floorf(v / 4.0f);
      out_pos[c * 3 + f] = v;
    }
    if (f == 63) out_batch[c] = (float)batch[nlist[o0]];
  }
}

__global__ void node_tail_k(const unsigned* __restrict__ hdr,
                            float* __restrict__ out_x, float* __restrict__ out_pos,
                            float* __restrict__ out_batch) {
  int ncl = (int)hdr[8];
  int total = (NN - ncl) * FF;
  for (int i = blockIdx.x * blockDim.x + threadIdx.x; i < total;
       i += gridDim.x * blockDim.x) {
    int r = ncl + (i >> 6), f = i & 63;
    out_x[(size_t)r * FF + f] = 0.0f;
    if (f < 3) out_pos[r * 3 + f] = 0.0f;
    if (f == 0) out_batch[r] = -1.0f;
  }
}

// ---- edge pipeline: coarse partition (r10) + 64-bin subpartition + r7 wave grouping ----

__global__ void __launch_bounds__(256)
coarse_cnt_k(const int* __restrict__ ei, const int* __restrict__ cluster,
             unsigned* __restrict__ mat) {
  __shared__ unsigned h[NBUCK];
  for (int i = threadIdx.x; i < NBUCK; i += 256) h[i] = 0u;
  __syncthreads();
  int t0 = blockIdx.x * TILE;
  for (int k = threadIdx.x; k < TILE; k += 256) {
    int t = t0 + k;
    if (t >= EE) break;
    unsigned s = (unsigned)cluster[ei[t]] & 0x1FFFFu;
    unsigned d = (unsigned)cluster[ei[EE + t]] & 0x1FFFFu;
    if (s != d) atomicAdd(&h[s >> 6], 1u);
  }
  __syncthreads();
  for (int i = threadIdx.x; i < NBUCK; i += 256)
    mat[(size_t)blockIdx.x * NBUCK + i] = h[i];
}

__global__ void transpose_k(const unsigned* __restrict__ mat, unsigned* __restrict__ matT) {
  int f = blockIdx.x * blockDim.x + threadIdx.x;
  if (f >= NSB * NBUCK) return;
  int cb = f / NSB, blk = f - cb * NSB;
  matT[f] = mat[(size_t)blk * NBUCK + cb];
}

// keys[p] = (s_low6 << 39) | (d << 22) | eid ; single-writer contiguous chunks
__global__ void __launch_bounds__(256)
coarse_scatter_k(const int* __restrict__ ei, const int* __restrict__ cluster,
                 const unsigned* __restrict__ matT, ull* __restrict__ keys) {
  __shared__ unsigned cur[NBUCK];
  for (int i = threadIdx.x; i < NBUCK; i += 256)
    cur[i] = matT[(size_t)i * NSB + blockIdx.x];
  __syncthreads();
  int t0 = blockIdx.x * TILE;
  for (int k = threadIdx.x; k < TILE; k += 256) {
    int t = t0 + k;
    if (t >= EE) break;
    unsigned s = (unsigned)cluster[ei[t]] & 0x1FFFFu;
    unsigned d = (unsigned)cluster[ei[EE + t]] & 0x1FFFFu;
    if (s == d) continue;
    unsigned p = atomicAdd(&cur[s >> 6], 1u);
    keys[p] = ((ull)(s & 63u) << 39) | ((ull)d << 22) | (unsigned)t;
  }
}

// per coarse bucket: 2-pass 64-bin partition by s_low6; writes cs_off and
// stripped keys (cd<<22|eid) to keys2. Tiny LDS -> high occupancy, no sort.
__global__ void __launch_bounds__(256)
subpart_k(const ull* __restrict__ keys, ull* __restrict__ keys2,
          const unsigned* __restrict__ matT, const unsigned* __restrict__ hdr,
          unsigned* __restrict__ cs_off) {
  __shared__ unsigned h[64], pre[64], cur[64];
  int cb = blockIdx.x;
  unsigned start = matT[(size_t)cb * NSB];
  unsigned end = (cb == NBUCK - 1) ? hdr[11] : matT[(size_t)(cb + 1) * NSB];
  int len = (int)(end - start);
  int tid = threadIdx.x;
  if (tid < 64) h[tid] = 0u;
  __syncthreads();
  for (int i = tid; i < len; i += 256)
    atomicAdd(&h[(unsigned)(keys[start + i] >> 39) & 63u], 1u);
  __syncthreads();
  if (tid == 0) {
    unsigned run = 0;
    for (int j = 0; j < 64; j++) { pre[j] = run; run += h[j]; }
  }
  __syncthreads();
  if (tid < 64) {
    cs_off[cb * 64 + tid] = start + pre[tid];
    cur[tid] = start + pre[tid];
  }
  if (cb == 0 && tid == 64) cs_off[NCS] = hdr[11];   // sentinel
  __syncthreads();
  for (int i = tid; i < len; i += 256) {
    ull v = keys[start + i];
    unsigned j = (unsigned)(v >> 39) & 63u;
    unsigned p = atomicAdd(&cur[j], 1u);
    keys2[p] = v & ((1ULL << 39) - 1ULL);
  }
}

// split non-empty cs buckets into small (len<=64) and big; wave-aggregated atomics
__global__ void compact_k(const unsigned* __restrict__ cs_off, unsigned* hdr,
                          int* __restrict__ nb_small, int* __restrict__ nb_big) {
  int b = blockIdx.x * blockDim.x + threadIdx.x;
  int lane = threadIdx.x & 63;
  int len = 0;
  if (b < NCS) len = (int)(cs_off[b + 1] - cs_off[b]);
  bool sm = (len > 0) && (len <= 64);
  bool bg = len > 64;
  ull msm = __ballot(sm);
  ull mbg = __ballot(bg);
  unsigned bs = 0, bb = 0;
  if (lane == 0) {
    if (msm) bs = atomicAdd(&hdr[9], (unsigned)__popcll(msm));
    if (mbg) bb = atomicAdd(&hdr[10], (unsigned)__popcll(mbg));
  }
  bs = (unsigned)__shfl((int)bs, 0);
  bb = (unsigned)__shfl((int)bb, 0);
  ull lt = (1ULL << lane) - 1ULL;
  if (sm) nb_small[bs + (unsigned)__popcll(msm & lt)] = b;
  if (bg) nb_big[bb + (unsigned)__popcll(mbg & lt)] = b;
}

// one wave per cs bucket: head-detect via readlane, store head MASK
__global__ void __launch_bounds__(256)
group_small_k(const ull* __restrict__ keys, const unsigned* __restrict__ cs_off,
              const int* __restrict__ nb_small, const unsigned* __restrict__ hdr,
              unsigned* __restrict__ grp_cnt, ull* __restrict__ headmask) {
  int w = (blockIdx.x * blockDim.x + threadIdx.x) >> 6;
  int nw = (gridDim.x * blockDim.x) >> 6;
  int lane = threadIdx.x & 63;
  int cnt = (int)hdr[9];
  for (int bi = w; bi < cnt; bi += nw) {
    int b = nb_small[bi];
    unsigned o0 = cs_off[b];
    int len = (int)(cs_off[b + 1] - o0);
    unsigned cdv = 0xFFFFFFFFu;
    if (lane < len) cdv = (unsigned)(__builtin_nontemporal_load(&keys[o0 + lane]) >> 22);
    bool head = (lane < len);
    for (int j = 0; j < len; ++j) {
      unsigned cj = (unsigned)__builtin_amdgcn_readlane((int)cdv, j);
      if (cj == cdv && j < lane) head = false;
    }
    ull M = __ballot(head);
    if (lane == 0) {
      grp_cnt[b] = (unsigned)__popcll(M);
      headmask[bi] = M;
    }
  }
}

// one wave per cs bucket: head mask precomputed; hoisted ea load; shfl merge
__global__ void __launch_bounds__(256)
emit_small_k(const ull* __restrict__ keys, const unsigned* __restrict__ cs_off,
             const int* __restrict__ nb_small, const unsigned* __restrict__ hdr,
             const unsigned* __restrict__ grp_base, const ull* __restrict__ headmask,
             const float* __restrict__ ea,
             float* __restrict__ out_src, float* __restrict__ out_dst,
             float* __restrict__ out_ea) {
  int w = (blockIdx.x * blockDim.x + threadIdx.x) >> 6;
  int nw = (gridDim.x * blockDim.x) >> 6;
  int lane = threadIdx.x & 63;
  int cnt = (int)hdr[9];
  for (int bi = w; bi < cnt; bi += nw) {
    int b = nb_small[bi];
    unsigned o0 = cs_off[b];
    int len = (int)(cs_off[b + 1] - o0);
    ull M = headmask[bi];
    unsigned cdv = 0xFFFFFFFFu, eidv = 0u;
    if (lane < len) {
      ull key = __builtin_nontemporal_load(&keys[o0 + lane]);
      cdv = (unsigned)(key >> 22);
      eidv = (unsigned)(key & 0x3FFFFFULL);
    }
    float4 v0 = make_float4(0.f, 0.f, 0.f, 0.f), v1 = v0;
    if (lane < len) {
      const float4* p = (const float4*)&ea[(size_t)eidv * FEA];
      v0 = p[0]; v1 = p[1];
    }
    bool head = (M >> lane) & 1ULL;
    bool allsingle = ((int)__popcll(M) == len);
    unsigned r = 0;
    for (int j = 0; j < len; ++j) {
      unsigned cj = (unsigned)__builtin_amdgcn_readlane((int)cdv, j);
      if (((M >> j) & 1ULL) && cj < cdv) r++;
    }
    float4 a0 = v0, a1 = v1;
    if (!allsingle) {
      for (int j = 0; j < len; ++j) {
        unsigned cj = (unsigned)__builtin_amdgcn_readlane((int)cdv, j);
        bool take = (cj == cdv) && (j != lane);
        float t0 = __shfl(v0.x, j), t1 = __shfl(v0.y, j);
        float t2 = __shfl(v0.z, j), t3 = __shfl(v0.w, j);
        float t4 = __shfl(v1.x, j), t5 = __shfl(v1.y, j);
        float t6 = __shfl(v1.z, j), t7 = __shfl(v1.w, j);
        if (take) {
          a0.x += t0; a0.y += t1; a0.z += t2; a0.w += t3;
          a1.x += t4; a1.y += t5; a1.z += t6; a1.w += t7;
        }
      }
    }
    if (head) {
      unsigned row = grp_base[b] + r;
      out_src[row] = (float)b;
      out_dst[row] = (float)cdv;
      float4* o = (float4*)&out_ea[(size_t)row * FEA];
      o[0] = a0; o[1] = a1;
    }
  }
}

__global__ void __launch_bounds__(256)
sort_big_k(ull* __restrict__ keys, const unsigned* __restrict__ cs_off,
           const int* __restrict__ nb_big, const unsigned* __restrict__ hdr,
           unsigned* __restrict__ grp_cnt) {
  __shared__ ull sm[LCAP];
  __shared__ ull rb[256];
  __shared__ int ri[256];
  __shared__ unsigned s4[4];
  int nbig = (int)hdr[10];
  for (int bi = blockIdx.x; bi < nbig; bi += gridDim.x) {
    int b = nb_big[bi];
    unsigned o0 = cs_off[b];
    int len = (int)(cs_off[b + 1] - o0);
    if (len <= LCAP) {
      int np = 1; while (np < len) np <<= 1;
      for (int i = threadIdx.x; i < np; i += 256)
        sm[i] = (i < len) ? keys[o0 + i] : ~0ULL;
      __syncthreads();
      for (int k = 2; k <= np; k <<= 1) {
        for (int j = k >> 1; j > 0; j >>= 1) {
          for (int i = threadIdx.x; i < np; i += 256) {
            int ixj = i ^ j;
            if (ixj > i) {
              ull a = sm[i], c = sm[ixj];
              bool up = ((i & k) == 0);
              if (up ? (a > c) : (a < c)) { sm[i] = c; sm[ixj] = a; }
            }
          }
          __syncthreads();
        }
      }
      unsigned g = 0;
      for (int i = threadIdx.x; i < len; i += 256) {
        ull kk = sm[i];
        keys[o0 + i] = kk;
        unsigned cd = (unsigned)(kk >> 22);
        if (i == 0 || (unsigned)(sm[i - 1] >> 22) != cd) g++;
      }
      for (int o = 32; o > 0; o >>= 1) g += __shfl_down(g, o);
      if ((threadIdx.x & 63) == 0) s4[threadIdx.x >> 6] = g;
      __syncthreads();
      if (threadIdx.x == 0) grp_cnt[b] = s4[0] + s4[1] + s4[2] + s4[3];
      __syncthreads();
    } else {
      for (int p = 0; p < len - 1; p++) {
        ull best = ~0ULL; int bidx = -1;
        for (int i = p + threadIdx.x; i < len; i += 256) {
          ull v = keys[o0 + i];
          if (v < best) { best = v; bidx = i; }
        }
        rb[threadIdx.x] = best; ri[threadIdx.x] = bidx;
        __syncthreads();
        for (int sd = 128; sd > 0; sd >>= 1) {
          if (threadIdx.x < sd && rb[threadIdx.x + sd] < rb[threadIdx.x]) {
            rb[threadIdx.x] = rb[threadIdx.x + sd]; ri[threadIdx.x] = ri[threadIdx.x + sd];
          }
          __syncthreads();
        }
        if (threadIdx.x == 0) {
          int m = ri[0];
          ull tmp = keys[o0 + p];
          keys[o0 + p] = rb[0];
          keys[o0 + m] = tmp;
        }
        __syncthreads();
      }
      unsigned g = 0;
      for (int i = threadIdx.x; i < len; i += 256) {
        unsigned cd = (unsigned)(keys[o0 + i] >> 22);
        if (i == 0 || (unsigned)(keys[o0 + i - 1] >> 22) != cd) g++;
      }
      for (int o = 32; o > 0; o >>= 1) g += __shfl_down(g, o);
      if ((threadIdx.x & 63) == 0) s4[threadIdx.x >> 6] = g;
      __syncthreads();
      if (threadIdx.x == 0) grp_cnt[b] = s4[0] + s4[1] + s4[2] + s4[3];
      __syncthreads();
    }
  }
}

__global__ void __launch_bounds__(256)
emit_big_k(const ull* __restrict__ keys, const unsigned* __restrict__ cs_off,
           const int* __restrict__ nb_big, const unsigned* __restrict__ hdr,
           const unsigned* __restrict__ grp_base, const float* __restrict__ ea,
           float* __restrict__ out_src, float* __restrict__ out_dst,
           float* __restrict__ out_ea) {
  __shared__ unsigned sc[256];
  __shared__ unsigned s_carry;
  int nbig = (int)hdr[10];
  for (int bi = blockIdx.x; bi < nbig; bi += gridDim.x) {
    int b = nb_big[bi];
    unsigned o0 = cs_off[b];
    int len = (int)(cs_off[b + 1] - o0);
    unsigned base = grp_base[b];
    if (threadIdx.x == 0) s_carry = 0;
    __syncthreads();
    for (int c0 = 0; c0 < len; c0 += 256) {
      int i = c0 + threadIdx.x;
      unsigned cd = 0; bool newg = false;
      if (i < len) {
        ull kk = keys[o0 + i];
        cd = (unsigned)(kk >> 22);
        newg = (i == 0) || ((unsigned)(keys[o0 + i - 1] >> 22) != cd);
      }
      unsigned flag = newg ? 1u : 0u;
      sc[threadIdx.x] = flag;
      __syncthreads();
      unsigned xv = flag;
      for (int o = 1; o < 256; o <<= 1) {
        unsigned y = (threadIdx.x >= o) ? sc[threadIdx.x - o] : 0u;
        __syncthreads();
        xv += y;
        sc[threadIdx.x] = xv;
        __syncthreads();
      }
      unsigned carry_old = s_carry;
      if (newg) {
        float a0=0,a1=0,a2=0,a3=0,a4=0,a5=0,a6=0,a7=0;
        int j = i;
        while (j < len) {
          ull k2 = keys[o0 + j];
          if ((unsigned)(k2 >> 22) != cd) break;
          unsigned eid = (unsigned)(k2 & 0x3FFFFFULL);
          const float* p = &ea[(size_t)eid * FEA];
          a0+=p[0];a1+=p[1];a2+=p[2];a3+=p[3];a4+=p[4];a5+=p[5];a6+=p[6];a7+=p[7];
          j++;
        }
        unsigned row = base + carry_old + xv - 1u;
        out_src[row] = (float)b;
        out_dst[row] = (float)cd;
        float* q = &out_ea[(size_t)row * FEA];
        q[0]=a0;q[1]=a1;q[2]=a2;q[3]=a3;q[4]=a4;q[5]=a5;q[6]=a6;q[7]=a7;
      }
      __syncthreads();
      if (threadIdx.x == 255) s_carry = carry_old + xv;
      __syncthreads();
    }
  }
}

__global__ void tail_fill_k(const unsigned* __restrict__ grp_base,
                            float* __restrict__ out_src, float* __restrict__ out_dst,
                            float* __restrict__ out_ea) {
  int T = (int)grp_base[NCS];
  for (int t = T + blockIdx.x * blockDim.x + threadIdx.x; t < EE;
       t += gridDim.x * blockDim.x) {
    out_src[t] = -1.0f;
    out_dst[t] = -1.0f;
    float4 z = make_float4(0.f, 0.f, 0.f, 0.f);
    float4* o = (float4*)&out_ea[(size_t)t * FEA];
    o[0] = z; o[1] = z;
  }
}

extern "C" void kernel_launch(void* const* d_in, const int* in_sizes, int n_in,
                              void* d_out, int out_size, void* d_ws, size_t ws_size,
                              hipStream_t stream) {
  const float* x   = (const float*)d_in[0];
  const float* pos = (const float*)d_in[1];
  const int* batch = (const int*)d_in[2];
  const int* ei    = (const int*)d_in[3];
  const float* ea  = (const float*)d_in[4];
  float* out = (float*)d_out;

  const size_t OX = 0;
  const size_t OP = (size_t)NN * FF;
  const size_t OB = OP + (size_t)NN * 3;
  const size_t OE = OB + (size_t)NN;
  const size_t OA = OE + (size_t)2 * EE;

  char* w = (char*)d_ws;
  size_t woff = 0;
  auto alloc = [&](size_t bytes) -> void* {
    void* p = w + woff;
    woff += (bytes + 255) & ~(size_t)255;
    return p;
  };
  // zeroed region (one memset)
  unsigned* rank    = (unsigned*)alloc((size_t)RAWCAP * 4);     // reuse: nb_big
  unsigned* cnt     = (unsigned*)alloc((size_t)(NN + 1) * 4);   // reuse: nb_small
  unsigned* grp_cnt = (unsigned*)alloc((size_t)(NCS + 1) * 4);
  ull* desc0        = (ull*)alloc(2048 * 8);
  ull* desc1        = (ull*)alloc(2048 * 8);
  ull* desc2        = (ull*)alloc(2048 * 8);
  ull* desc3        = (ull*)alloc(2048 * 8);
  size_t zero_bytes = woff;
  // written-before-read region
  int* cluster      = (int*)alloc((size_t)NN * 4);
  int* nlist        = (int*)alloc((size_t)NN * 4);
  unsigned* node_off= (unsigned*)alloc((size_t)(NN + 2) * 4);
  unsigned* mat     = (unsigned*)alloc((size_t)NSB * NBUCK * 4);
  unsigned* matT    = (unsigned*)alloc((size_t)NSB * NBUCK * 4);
  unsigned* cs_off  = (unsigned*)alloc((size_t)(NCS + 2) * 4);
  unsigned* grp_base= (unsigned*)alloc((size_t)(NCS + 2) * 4);
  unsigned* hdr     = (unsigned*)alloc(256);
  ull* headmask     = (ull*)alloc((size_t)NN * 8);
  ull* keys         = (ull*)alloc((size_t)EE * 8);
  ull* keys2        = (ull*)alloc((size_t)EE * 8);

  int* nb_small = (int*)cnt;    // dead after node_off scan
  int* nb_big   = (int*)rank;   // dead after node_cnt_k

  hipMemsetAsync(d_ws, 0, zero_bytes, stream);

  init_hdr_k<<<1, 64, 0, stream>>>(hdr);
  minmax_k<<<128, 256, 0, stream>>>(pos, hdr);
  dims_k<<<1, 64, 0, stream>>>(hdr);
  raw_k<<<(NN + 255) / 256, 256, 0, stream>>>(pos, batch, hdr, cluster, rank);

  auto scan1 = [&](const unsigned* in_, unsigned* out_, int ntot,
                   unsigned* total_out, ull* d_) {
    int nb = (ntot + 1023) / 1024;
    scan_lb_k<<<nb, 256, 0, stream>>>(in_, out_, ntot, total_out, d_, nb);
  };
  scan1(rank, rank, RAWCAP, hdr + 8, desc0);   // rank[raw]=cluster id; total->ncl

  node_cnt_k<<<(NN + 255) / 256, 256, 0, stream>>>(rank, cluster, cnt);
  scan1(cnt, node_off, NN + 1, nullptr, desc1);
  node_scatter_k<<<(NN + 255) / 256, 256, 0, stream>>>(cluster, node_off, nlist);
  cluster_reduce_k<<<2048, 256, 0, stream>>>(x, pos, batch, nlist, node_off, hdr,
                                             out + OX, out + OP, out + OB);
  node_tail_k<<<2048, 256, 0, stream>>>(hdr, out + OX, out + OP, out + OB);

  coarse_cnt_k<<<NSB, 256, 0, stream>>>(ei, cluster, mat);
  transpose_k<<<(NSB * NBUCK + 255) / 256, 256, 0, stream>>>(mat, matT);
  scan1(matT, matT, NSB * NBUCK, hdr + 11, desc2);   // chunk offsets; total->Etot
  coarse_scatter_k<<<NSB, 256, 0, stream>>>(ei, cluster, matT, keys);
  subpart_k<<<NBUCK, 256, 0, stream>>>(keys, keys2, matT, hdr, cs_off);

  compact_k<<<(NCS + 255) / 256, 256, 0, stream>>>(cs_off, hdr, nb_small, nb_big);
  group_small_k<<<2048, 256, 0, stream>>>(keys2, cs_off, nb_small, hdr, grp_cnt, headmask);
  sort_big_k<<<256, 256, 0, stream>>>(keys2, cs_off, nb_big, hdr, grp_cnt);
  scan1(grp_cnt, grp_base, NCS + 1, nullptr, desc3);
  emit_small_k<<<4096, 256, 0, stream>>>(keys2, cs_off, nb_small, hdr, grp_base, headmask, ea,
                                         out + OE, out + OE + EE, out + OA);
  emit_big_k<<<256, 256, 0, stream>>>(keys2, cs_off, nb_big, hdr, grp_base, ea,
                                      out + OE, out + OE + EE, out + OA);
  tail_fill_k<<<512, 256, 0, stream>>>(grp_base, out + OE, out + OE + EE, out + OA);
}

// Round 12
// 507.817 us; speedup vs baseline: 1.3430x; 1.0096x over previous
//
#include <hip/hip_runtime.h>

#define NN 300000
#define FF 64
#define EE 2400000
#define FEA 8
#define RAWCAP 131072   // >= 8*129*97 = 100104 (so cluster ids < 2^17)
#define NCS 131072      // cs id space (== RAWCAP)
#define NBUCK 2048      // coarse buckets: cb = cs>>6
#define NSB 512         // scatter blocks
#define TILE ((EE + NSB - 1) / NSB)
#define CAP 2560        // LDS staging capacity per coarse bucket (mean ~1172)
#define LCAP 2048       // big-bucket bitonic capacity

typedef unsigned long long ull;

__device__ __forceinline__ unsigned fenc(float f) {
  unsigned b = __float_as_uint(f);
  return (b & 0x80000000u) ? ~b : (b | 0x80000000u);
}
__device__ __forceinline__ float fdec(unsigned e) {
  unsigned b = (e & 0x80000000u) ? (e ^ 0x80000000u) : ~e;
  return __uint_as_float(b);
}

__global__ void init_hdr_k(unsigned* hdr) {
  if (threadIdx.x == 0) {
    hdr[0] = 0xFFFFFFFFu; hdr[1] = 0xFFFFFFFFu;  // min enc
    hdr[2] = 0u;          hdr[3] = 0u;           // max enc
    hdr[9] = 0u;          hdr[10] = 0u;          // compact-list counters
  }
}

__global__ void minmax_k(const float* __restrict__ pos, unsigned* hdr) {
  __shared__ unsigned red[4][4];
  int t = blockIdx.x * blockDim.x + threadIdx.x;
  float mnx = 1e30f, mny = 1e30f, mxx = -1e30f, mxy = -1e30f;
  for (int i = t; i < NN; i += gridDim.x * blockDim.x) {
    float px = pos[i * 3 + 1], py = pos[i * 3 + 2];
    mnx = fminf(mnx, px); mny = fminf(mny, py);
    mxx = fmaxf(mxx, px); mxy = fmaxf(mxy, py);
  }
  for (int o = 1; o < 64; o <<= 1) {
    mnx = fminf(mnx, __shfl_xor(mnx, o));
    mny = fminf(mny, __shfl_xor(mny, o));
    mxx = fmaxf(mxx, __shfl_xor(mxx, o));
    mxy = fmaxf(mxy, __shfl_xor(mxy, o));
  }
  int wid = threadIdx.x >> 6;
  if ((threadIdx.x & 63) == 0) {
    red[wid][0] = fenc(mnx); red[wid][1] = fenc(mny);
    red[wid][2] = fenc(mxx); red[wid][3] = fenc(mxy);
  }
  __syncthreads();
  if (threadIdx.x == 0) {
    unsigned a0 = red[0][0], a1 = red[0][1], a2 = red[0][2], a3 = red[0][3];
    for (int k = 1; k < 4; k++) {
      a0 = min(a0, red[k][0]); a1 = min(a1, red[k][1]);
      a2 = max(a2, red[k][2]); a3 = max(a3, red[k][3]);
    }
    atomicMin(&hdr[0], a0); atomicMin(&hdr[1], a1);
    atomicMax(&hdr[2], a2); atomicMax(&hdr[3], a3);
  }
}

__global__ void dims_k(unsigned* hdr) {
  if (threadIdx.x == 0 && blockIdx.x == 0) {
    float mnx = fdec(hdr[0]), mny = fdec(hdr[1]);
    float mxx = fdec(hdr[2]), mxy = fdec(hdr[3]);
    int d0 = (int)(floorf((mxx - mnx) / 5.0f) + 1.0f);
    int d1 = (int)(floorf((mxy - mny) / 5.0f) + 1.0f);
    hdr[4] = (unsigned)d0;
    hdr[5] = (unsigned)d1;
    ((float*)hdr)[6] = mnx;
    ((float*)hdr)[7] = mny;
  }
}

__global__ void raw_k(const float* __restrict__ pos, const int* __restrict__ batch,
                      const unsigned* __restrict__ hdr, int* __restrict__ cluster,
                      unsigned* __restrict__ flags) {
  int i = blockIdx.x * blockDim.x + threadIdx.x;
  if (i >= NN) return;
  float mnx = ((const float*)hdr)[6], mny = ((const float*)hdr)[7];
  int d0 = (int)hdr[4], d1 = (int)hdr[5];
  int c0 = (int)floorf((pos[i * 3 + 1] - mnx) / 5.0f);
  int c1 = (int)floorf((pos[i * 3 + 2] - mny) / 5.0f);
  int raw = batch[i] * (d0 * d1) + c0 * d1 + c1;
  cluster[i] = raw;
  flags[raw] = 1u;
}

// single-kernel exclusive scan: decoupled lookback (validated r8-r11)
__global__ void __launch_bounds__(256)
scan_lb_k(const unsigned* __restrict__ in, unsigned* __restrict__ out, int ntot,
          unsigned* __restrict__ total_out, ull* __restrict__ desc, int nb) {
  __shared__ unsigned sc[256];
  __shared__ unsigned s_pref;
  int bid = blockIdx.x;
  int base = bid * 1024 + threadIdx.x * 4;
  unsigned v[4]; unsigned s = 0;
#pragma unroll
  for (int k = 0; k < 4; k++) {
    int i = base + k;
    v[k] = (i < ntot) ? in[i] : 0u;
    s += v[k];
  }
  sc[threadIdx.x] = s;
  __syncthreads();
  unsigned xv = s;
  for (int o = 1; o < 256; o <<= 1) {
    unsigned y = (threadIdx.x >= o) ? sc[threadIdx.x - o] : 0u;
    __syncthreads();
    xv += y;
    sc[threadIdx.x] = xv;
    __syncthreads();
  }
  unsigned btot = sc[255];
  if (threadIdx.x == 0) {
    unsigned ex = 0;
    if (bid == 0) {
      atomicExch(&desc[0], (2ULL << 32) | (ull)btot);
    } else {
      atomicExch(&desc[bid], (1ULL << 32) | (ull)btot);
      int p = bid - 1;
      while (true) {
        ull d = atomicAdd(&desc[p], 0ULL);
        unsigned fl = (unsigned)(d >> 32);
        if (fl == 2u) { ex += (unsigned)d; break; }
        if (fl == 1u) { ex += (unsigned)d; --p; }
      }
      atomicExch(&desc[bid], (2ULL << 32) | (ull)(ex + btot));
    }
    s_pref = ex;
    if (total_out && bid == nb - 1) *total_out = ex + btot;
  }
  __syncthreads();
  unsigned run = s_pref + xv - s;
#pragma unroll
  for (int k = 0; k < 4; k++) {
    int i = base + k;
    if (i < ntot) out[i] = run;
    run += v[k];
  }
}

// map raw->cluster id, count members, pack slot r into cluster: (r<<17)|cl
__global__ void node_cnt_k(const unsigned* __restrict__ rank, int* __restrict__ cluster,
                           unsigned* __restrict__ cnt) {
  int i = blockIdx.x * blockDim.x + threadIdx.x;
  if (i >= NN) return;
  unsigned cl = rank[cluster[i]];
  unsigned r = atomicAdd(&cnt[cl], 1u);
  cluster[i] = (int)((r << 17) | cl);
}

// atomic-free: position = node_off[cl] + packed slot
__global__ void node_scatter_k(const int* __restrict__ cluster,
                               const unsigned* __restrict__ node_off,
                               int* __restrict__ nlist) {
  int i = blockIdx.x * blockDim.x + threadIdx.x;
  if (i >= NN) return;
  unsigned c = (unsigned)cluster[i];
  nlist[node_off[c & 0x1FFFFu] + (c >> 17)] = i;
}

// one wave per cluster: gather member rows, fmax in registers, write once.
__global__ void __launch_bounds__(256)
cluster_reduce_k(const float* __restrict__ x, const float* __restrict__ pos,
                 const int* __restrict__ batch, const int* __restrict__ nlist,
                 const unsigned* __restrict__ node_off, const unsigned* __restrict__ hdr,
                 float* __restrict__ out_x, float* __restrict__ out_pos,
                 float* __restrict__ out_batch) {
  int w = (blockIdx.x * blockDim.x + threadIdx.x) >> 6;
  int nw = (gridDim.x * blockDim.x) >> 6;
  int f = threadIdx.x & 63;
  int ncl = (int)hdr[8];
  for (int c = w; c < ncl; c += nw) {
    unsigned o0 = node_off[c];
    int len = (int)(node_off[c + 1] - o0);
    float mx = -1e38f;
    long long ps = 0;
    for (int m = 0; m < len; m++) {
      int nd = nlist[o0 + m];
      mx = fmaxf(mx, x[(size_t)nd * FF + f]);
      if (f < 3) ps += (long long)llrintf(pos[nd * 3 + f] * 65536.0f);
    }
    out_x[(size_t)c * FF + f] = mx;
    if (f < 3) {
      float v = (float)((double)ps / 65536.0 / (double)len);
      if (f > 0) v = floorf(v / 4.0f);
      out_pos[c * 3 + f] = v;
    }
    if (f == 63) out_batch[c] = (float)batch[nlist[o0]];
  }
}

__global__ void node_tail_k(const unsigned* __restrict__ hdr,
                            float* __restrict__ out_x, float* __restrict__ out_pos,
                            float* __restrict__ out_batch) {
  int ncl = (int)hdr[8];
  int total = (NN - ncl) * FF;
  for (int i = blockIdx.x * blockDim.x + threadIdx.x; i < total;
       i += gridDim.x * blockDim.x) {
    int r = ncl + (i >> 6), f = i & 63;
    out_x[(size_t)r * FF + f] = 0.0f;
    if (f < 3) out_pos[r * 3 + f] = 0.0f;
    if (f == 0) out_batch[r] = -1.0f;
  }
}

// ---- edge pipeline ----

__global__ void __launch_bounds__(256)
coarse_cnt_k(const int* __restrict__ ei, const int* __restrict__ cluster,
             unsigned* __restrict__ mat) {
  __shared__ unsigned h[NBUCK];
  for (int i = threadIdx.x; i < NBUCK; i += 256) h[i] = 0u;
  __syncthreads();
  int t0 = blockIdx.x * TILE;
  for (int k = threadIdx.x; k < TILE; k += 256) {
    int t = t0 + k;
    if (t >= EE) break;
    unsigned s = (unsigned)cluster[ei[t]] & 0x1FFFFu;
    unsigned d = (unsigned)cluster[ei[EE + t]] & 0x1FFFFu;
    if (s != d) atomicAdd(&h[s >> 6], 1u);
  }
  __syncthreads();
  for (int i = threadIdx.x; i < NBUCK; i += 256)
    mat[(size_t)blockIdx.x * NBUCK + i] = h[i];
}

__global__ void transpose_k(const unsigned* __restrict__ mat, unsigned* __restrict__ matT) {
  int f = blockIdx.x * blockDim.x + threadIdx.x;
  if (f >= NSB * NBUCK) return;
  int cb = f / NSB, blk = f - cb * NSB;
  matT[f] = mat[(size_t)blk * NBUCK + cb];
}

// keys[p] = (s_low6 << 39) | (d << 22) | eid ; single-writer contiguous chunks
__global__ void __launch_bounds__(256)
coarse_scatter_k(const int* __restrict__ ei, const int* __restrict__ cluster,
                 const unsigned* __restrict__ matT, ull* __restrict__ keys) {
  __shared__ unsigned cur[NBUCK];
  for (int i = threadIdx.x; i < NBUCK; i += 256)
    cur[i] = matT[(size_t)i * NSB + blockIdx.x];
  __syncthreads();
  int t0 = blockIdx.x * TILE;
  for (int k = threadIdx.x; k < TILE; k += 256) {
    int t = t0 + k;
    if (t >= EE) break;
    unsigned s = (unsigned)cluster[ei[t]] & 0x1FFFFu;
    unsigned d = (unsigned)cluster[ei[EE + t]] & 0x1FFFFu;
    if (s == d) continue;
    unsigned p = atomicAdd(&cur[s >> 6], 1u);
    keys[p] = ((ull)(s & 63u) << 39) | ((ull)d << 22) | (unsigned)t;
  }
}

// FUSED: per coarse bucket -- LDS staging, 64-bin partition (coalesced keys2
// write-back), wave-level group detect (headmask/grp_cnt by cs id), and
// small/big list building with ONE global atomic per list per block.
__global__ void __launch_bounds__(256)
subgrp_k(const ull* __restrict__ keys, ull* __restrict__ keys2,
         const unsigned* __restrict__ matT, unsigned* __restrict__ hdr,
         unsigned* __restrict__ cs_off, unsigned* __restrict__ grp_cnt,
         ull* __restrict__ headmask, int* __restrict__ nb_small,
         int* __restrict__ nb_big) {
  __shared__ ull sk[CAP];
  __shared__ ull sk2[CAP];
  __shared__ unsigned h[64], pre[65], cur[64];
  __shared__ unsigned char sm_list[64], bg_list[64];
  __shared__ unsigned cnt_sm, cnt_bg, base_sm, base_bg;
  int cb = blockIdx.x;
  unsigned start = matT[(size_t)cb * NSB];
  unsigned end = (cb == NBUCK - 1) ? hdr[11] : matT[(size_t)(cb + 1) * NSB];
  int len = (int)(end - start);
  int tid = threadIdx.x;
  int wid = tid >> 6, lane = tid & 63;
  if (tid == 0) { cnt_sm = 0u; cnt_bg = 0u; }
  if (tid < 64) h[tid] = 0u;
  if (cb == 0 && tid == 65) cs_off[NCS] = hdr[11];   // sentinel
  __syncthreads();
  bool lds = (len <= CAP);
  if (lds) {
    for (int i = tid; i < len; i += 256) {
      ull v = keys[start + i];
      sk[i] = v;
      atomicAdd(&h[(unsigned)(v >> 39) & 63u], 1u);
    }
  } else {
    for (int i = tid; i < len; i += 256)
      atomicAdd(&h[(unsigned)(keys[start + i] >> 39) & 63u], 1u);
  }
  __syncthreads();
  if (tid == 0) {
    unsigned run = 0;
    for (int j = 0; j < 64; j++) { pre[j] = run; run += h[j]; }
    pre[64] = run;
  }
  __syncthreads();
  if (tid < 64) { cs_off[cb * 64 + tid] = start + pre[tid]; cur[tid] = pre[tid]; }
  __syncthreads();
  if (lds) {
    for (int i = tid; i < len; i += 256) {
      ull v = sk[i];
      unsigned j = (unsigned)(v >> 39) & 63u;
      unsigned p = atomicAdd(&cur[j], 1u);
      sk2[p] = v & ((1ULL << 39) - 1ULL);
    }
    __syncthreads();
    for (int i = tid; i < len; i += 256) keys2[start + i] = sk2[i];
    // group phase: one wave per cs sub-bucket
    for (int j = wid; j < 64; j += 4) {
      int lj = (int)(pre[j + 1] - pre[j]);
      if (lj == 0) continue;
      if (lj <= 64) {
        unsigned cdv = 0xFFFFFFFFu;
        if (lane < lj) cdv = (unsigned)(sk2[pre[j] + lane] >> 22);
        bool head = (lane < lj);
        for (int q = 0; q < lj; ++q) {
          unsigned cq = (unsigned)__builtin_amdgcn_readlane((int)cdv, q);
          if (cq == cdv && q < lane) head = false;
        }
        ull M = __ballot(head);
        if (lane == 0) {
          grp_cnt[cb * 64 + j] = (unsigned)__popcll(M);
          headmask[cb * 64 + j] = M;
          unsigned slot = atomicAdd(&cnt_sm, 1u);
          sm_list[slot] = (unsigned char)j;
        }
      } else {
        if (lane == 0) {
          unsigned slot = atomicAdd(&cnt_bg, 1u);
          bg_list[slot] = (unsigned char)j;
        }
      }
    }
  } else {
    // insurance path (oversized bucket): global-memory partition; all
    // non-empty sub-buckets routed to the big path.
    for (int i = tid; i < len; i += 256) {
      ull v = keys[start + i];
      unsigned j = (unsigned)(v >> 39) & 63u;
      unsigned p = atomicAdd(&cur[j], 1u);
      keys2[start + p] = v & ((1ULL << 39) - 1ULL);
    }
    __syncthreads();
    if (tid < 64 && (pre[tid + 1] - pre[tid]) > 0) {
      unsigned slot = atomicAdd(&cnt_bg, 1u);
      bg_list[slot] = (unsigned char)tid;
    }
  }
  __syncthreads();
  if (tid == 0) {
    if (cnt_sm) base_sm = atomicAdd(&hdr[9], cnt_sm);
    if (cnt_bg) base_bg = atomicAdd(&hdr[10], cnt_bg);
  }
  __syncthreads();
  if (tid < cnt_sm) nb_small[base_sm + tid] = cb * 64 + (int)sm_list[tid];
  if (tid >= 64 && (unsigned)(tid - 64) < cnt_bg)
    nb_big[base_bg + (tid - 64)] = cb * 64 + (int)bg_list[tid - 64];
}

// one wave per cs bucket: head mask precomputed; hoisted ea load; shfl merge
__global__ void __launch_bounds__(256)
emit_small_k(const ull* __restrict__ keys, const unsigned* __restrict__ cs_off,
             const int* __restrict__ nb_small, const unsigned* __restrict__ hdr,
             const unsigned* __restrict__ grp_base, const ull* __restrict__ headmask,
             const float* __restrict__ ea,
             float* __restrict__ out_src, float* __restrict__ out_dst,
             float* __restrict__ out_ea) {
  int w = (blockIdx.x * blockDim.x + threadIdx.x) >> 6;
  int nw = (gridDim.x * blockDim.x) >> 6;
  int lane = threadIdx.x & 63;
  int cnt = (int)hdr[9];
  for (int bi = w; bi < cnt; bi += nw) {
    int b = nb_small[bi];
    unsigned o0 = cs_off[b];
    int len = (int)(cs_off[b + 1] - o0);
    ull M = headmask[b];
    unsigned cdv = 0xFFFFFFFFu, eidv = 0u;
    if (lane < len) {
      ull key = __builtin_nontemporal_load(&keys[o0 + lane]);
      cdv = (unsigned)(key >> 22);
      eidv = (unsigned)(key & 0x3FFFFFULL);
    }
    float4 v0 = make_float4(0.f, 0.f, 0.f, 0.f), v1 = v0;
    if (lane < len) {
      const float4* p = (const float4*)&ea[(size_t)eidv * FEA];
      v0 = p[0]; v1 = p[1];
    }
    bool head = (M >> lane) & 1ULL;
    bool allsingle = ((int)__popcll(M) == len);
    unsigned r = 0;
    for (int j = 0; j < len; ++j) {
      unsigned cj = (unsigned)__builtin_amdgcn_readlane((int)cdv, j);
      if (((M >> j) & 1ULL) && cj < cdv) r++;
    }
    float4 a0 = v0, a1 = v1;
    if (!allsingle) {
      for (int j = 0; j < len; ++j) {
        unsigned cj = (unsigned)__builtin_amdgcn_readlane((int)cdv, j);
        bool take = (cj == cdv) && (j != lane);
        float t0 = __shfl(v0.x, j), t1 = __shfl(v0.y, j);
        float t2 = __shfl(v0.z, j), t3 = __shfl(v0.w, j);
        float t4 = __shfl(v1.x, j), t5 = __shfl(v1.y, j);
        float t6 = __shfl(v1.z, j), t7 = __shfl(v1.w, j);
        if (take) {
          a0.x += t0; a0.y += t1; a0.z += t2; a0.w += t3;
          a1.x += t4; a1.y += t5; a1.z += t6; a1.w += t7;
        }
      }
    }
    if (head) {
      unsigned row = grp_base[b] + r;
      out_src[row] = (float)b;
      out_dst[row] = (float)cdv;
      float4* o = (float4*)&out_ea[(size_t)row * FEA];
      o[0] = a0; o[1] = a1;
    }
  }
}

__global__ void __launch_bounds__(256)
sort_big_k(ull* __restrict__ keys, const unsigned* __restrict__ cs_off,
           const int* __restrict__ nb_big, const unsigned* __restrict__ hdr,
           unsigned* __restrict__ grp_cnt) {
  __shared__ ull sm[LCAP];
  __shared__ ull rb[256];
  __shared__ int ri[256];
  __shared__ unsigned s4[4];
  int nbig = (int)hdr[10];
  for (int bi = blockIdx.x; bi < nbig; bi += gridDim.x) {
    int b = nb_big[bi];
    unsigned o0 = cs_off[b];
    int len = (int)(cs_off[b + 1] - o0);
    if (len <= LCAP) {
      int np = 1; while (np < len) np <<= 1;
      for (int i = threadIdx.x; i < np; i += 256)
        sm[i] = (i < len) ? keys[o0 + i] : ~0ULL;
      __syncthreads();
      for (int k = 2; k <= np; k <<= 1) {
        for (int j = k >> 1; j > 0; j >>= 1) {
          for (int i = threadIdx.x; i < np; i += 256) {
            int ixj = i ^ j;
            if (ixj > i) {
              ull a = sm[i], c = sm[ixj];
              bool up = ((i & k) == 0);
              if (up ? (a > c) : (a < c)) { sm[i] = c; sm[ixj] = a; }
            }
          }
          __syncthreads();
        }
      }
      unsigned g = 0;
      for (int i = threadIdx.x; i < len; i += 256) {
        ull kk = sm[i];
        keys[o0 + i] = kk;
        unsigned cd = (unsigned)(kk >> 22);
        if (i == 0 || (unsigned)(sm[i - 1] >> 22) != cd) g++;
      }
      for (int o = 32; o > 0; o >>= 1) g += __shfl_down(g, o);
      if ((threadIdx.x & 63) == 0) s4[threadIdx.x >> 6] = g;
      __syncthreads();
      if (threadIdx.x == 0) grp_cnt[b] = s4[0] + s4[1] + s4[2] + s4[3];
      __syncthreads();
    } else {
      for (int p = 0; p < len - 1; p++) {
        ull best = ~0ULL; int bidx = -1;
        for (int i = p + threadIdx.x; i < len; i += 256) {
          ull v = keys[o0 + i];
          if (v < best) { best = v; bidx = i; }
        }
        rb[threadIdx.x] = best; ri[threadIdx.x] = bidx;
        __syncthreads();
        for (int sd = 128; sd > 0; sd >>= 1) {
          if (threadIdx.x < sd && rb[threadIdx.x + sd] < rb[threadIdx.x]) {
            rb[threadIdx.x] = rb[threadIdx.x + sd]; ri[threadIdx.x] = ri[threadIdx.x + sd];
          }
          __syncthreads();
        }
        if (threadIdx.x == 0) {
          int m = ri[0];
          ull tmp = keys[o0 + p];
          keys[o0 + p] = rb[0];
          keys[o0 + m] = tmp;
        }
        __syncthreads();
      }
      unsigned g = 0;
      for (int i = threadIdx.x; i < len; i += 256) {
        unsigned cd = (unsigned)(keys[o0 + i] >> 22);
        if (i == 0 || (unsigned)(keys[o0 + i - 1] >> 22) != cd) g++;
      }
      for (int o = 32; o > 0; o >>= 1) g += __shfl_down(g, o);
      if ((threadIdx.x & 63) == 0) s4[threadIdx.x >> 6] = g;
      __syncthreads();
      if (threadIdx.x == 0) grp_cnt[b] = s4[0] + s4[1] + s4[2] + s4[3];
      __syncthreads();
    }
  }
}

__global__ void __launch_bounds__(256)
emit_big_k(const ull* __restrict__ keys, const unsigned* __restrict__ cs_off,
           const int* __restrict__ nb_big, const unsigned* __restrict__ hdr,
           const unsigned* __restrict__ grp_base, const float* __restrict__ ea,
           float* __restrict__ out_src, float* __restrict__ out_dst,
           float* __restrict__ out_ea) {
  __shared__ unsigned sc[256];
  __shared__ unsigned s_carry;
  int nbig = (int)hdr[10];
  for (int bi = blockIdx.x; bi < nbig; bi += gridDim.x) {
    int b = nb_big[bi];
    unsigned o0 = cs_off[b];
    int len = (int)(cs_off[b + 1] - o0);
    unsigned base = grp_base[b];
    if (threadIdx.x == 0) s_carry = 0;
    __syncthreads();
    for (int c0 = 0; c0 < len; c0 += 256) {
      int i = c0 + threadIdx.x;
      unsigned cd = 0; bool newg = false;
      if (i < len) {
        ull kk = keys[o0 + i];
        cd = (unsigned)(kk >> 22);
        newg = (i == 0) || ((unsigned)(keys[o0 + i - 1] >> 22) != cd);
      }
      unsigned flag = newg ? 1u : 0u;
      sc[threadIdx.x] = flag;
      __syncthreads();
      unsigned xv = flag;
      for (int o = 1; o < 256; o <<= 1) {
        unsigned y = (threadIdx.x >= o) ? sc[threadIdx.x - o] : 0u;
        __syncthreads();
        xv += y;
        sc[threadIdx.x] = xv;
        __syncthreads();
      }
      unsigned carry_old = s_carry;
      if (newg) {
        float a0=0,a1=0,a2=0,a3=0,a4=0,a5=0,a6=0,a7=0;
        int j = i;
        while (j < len) {
          ull k2 = keys[o0 + j];
          if ((unsigned)(k2 >> 22) != cd) break;
          unsigned eid = (unsigned)(k2 & 0x3FFFFFULL);
          const float* p = &ea[(size_t)eid * FEA];
          a0+=p[0];a1+=p[1];a2+=p[2];a3+=p[3];a4+=p[4];a5+=p[5];a6+=p[6];a7+=p[7];
          j++;
        }
        unsigned row = base + carry_old + xv - 1u;
        out_src[row] = (float)b;
        out_dst[row] = (float)cd;
        float* q = &out_ea[(size_t)row * FEA];
        q[0]=a0;q[1]=a1;q[2]=a2;q[3]=a3;q[4]=a4;q[5]=a5;q[6]=a6;q[7]=a7;
      }
      __syncthreads();
      if (threadIdx.x == 255) s_carry = carry_old + xv;
      __syncthreads();
    }
  }
}

__global__ void tail_fill_k(const unsigned* __restrict__ grp_base,
                            float* __restrict__ out_src, float* __restrict__ out_dst,
                            float* __restrict__ out_ea) {
  int T = (int)grp_base[NCS];
  for (int t = T + blockIdx.x * blockDim.x + threadIdx.x; t < EE;
       t += gridDim.x * blockDim.x) {
    out_src[t] = -1.0f;
    out_dst[t] = -1.0f;
    float4 z = make_float4(0.f, 0.f, 0.f, 0.f);
    float4* o = (float4*)&out_ea[(size_t)t * FEA];
    o[0] = z; o[1] = z;
  }
}

extern "C" void kernel_launch(void* const* d_in, const int* in_sizes, int n_in,
                              void* d_out, int out_size, void* d_ws, size_t ws_size,
                              hipStream_t stream) {
  const float* x   = (const float*)d_in[0];
  const float* pos = (const float*)d_in[1];
  const int* batch = (const int*)d_in[2];
  const int* ei    = (const int*)d_in[3];
  const float* ea  = (const float*)d_in[4];
  float* out = (float*)d_out;

  const size_t OX = 0;
  const size_t OP = (size_t)NN * FF;
  const size_t OB = OP + (size_t)NN * 3;
  const size_t OE = OB + (size_t)NN;
  const size_t OA = OE + (size_t)2 * EE;

  char* w = (char*)d_ws;
  size_t woff = 0;
  auto alloc = [&](size_t bytes) -> void* {
    void* p = w + woff;
    woff += (bytes + 255) & ~(size_t)255;
    return p;
  };
  // zeroed region (one memset)
  unsigned* rank    = (unsigned*)alloc((size_t)RAWCAP * 4);     // reuse: nb_big
  unsigned* cnt     = (unsigned*)alloc((size_t)(NN + 1) * 4);   // reuse: nb_small
  unsigned* grp_cnt = (unsigned*)alloc((size_t)(NCS + 1) * 4);
  ull* desc0        = (ull*)alloc(2048 * 8);
  ull* desc1        = (ull*)alloc(2048 * 8);
  ull* desc2        = (ull*)alloc(2048 * 8);
  ull* desc3        = (ull*)alloc(2048 * 8);
  size_t zero_bytes = woff;
  // written-before-read region
  int* cluster      = (int*)alloc((size_t)NN * 4);
  int* nlist        = (int*)alloc((size_t)NN * 4);
  unsigned* node_off= (unsigned*)alloc((size_t)(NN + 2) * 4);
  unsigned* mat     = (unsigned*)alloc((size_t)NSB * NBUCK * 4);
  unsigned* matT    = (unsigned*)alloc((size_t)NSB * NBUCK * 4);
  unsigned* cs_off  = (unsigned*)alloc((size_t)(NCS + 2) * 4);
  unsigned* grp_base= (unsigned*)alloc((size_t)(NCS + 2) * 4);
  unsigned* hdr     = (unsigned*)alloc(256);
  ull* headmask     = (ull*)alloc((size_t)NCS * 8);
  ull* keys         = (ull*)alloc((size_t)EE * 8);
  ull* keys2        = (ull*)alloc((size_t)EE * 8);

  int* nb_small = (int*)cnt;    // dead after node_off scan
  int* nb_big   = (int*)rank;   // dead after node_cnt_k

  hipMemsetAsync(d_ws, 0, zero_bytes, stream);

  init_hdr_k<<<1, 64, 0, stream>>>(hdr);
  minmax_k<<<128, 256, 0, stream>>>(pos, hdr);
  dims_k<<<1, 64, 0, stream>>>(hdr);
  raw_k<<<(NN + 255) / 256, 256, 0, stream>>>(pos, batch, hdr, cluster, rank);

  auto scan1 = [&](const unsigned* in_, unsigned* out_, int ntot,
                   unsigned* total_out, ull* d_) {
    int nb = (ntot + 1023) / 1024;
    scan_lb_k<<<nb, 256, 0, stream>>>(in_, out_, ntot, total_out, d_, nb);
  };
  scan1(rank, rank, RAWCAP, hdr + 8, desc0);   // rank[raw]=cluster id; total->ncl

  node_cnt_k<<<(NN + 255) / 256, 256, 0, stream>>>(rank, cluster, cnt);
  scan1(cnt, node_off, NN + 1, nullptr, desc1);
  node_scatter_k<<<(NN + 255) / 256, 256, 0, stream>>>(cluster, node_off, nlist);
  cluster_reduce_k<<<2048, 256, 0, stream>>>(x, pos, batch, nlist, node_off, hdr,
                                             out + OX, out + OP, out + OB);
  node_tail_k<<<2048, 256, 0, stream>>>(hdr, out + OX, out + OP, out + OB);

  coarse_cnt_k<<<NSB, 256, 0, stream>>>(ei, cluster, mat);
  transpose_k<<<(NSB * NBUCK + 255) / 256, 256, 0, stream>>>(mat, matT);
  scan1(matT, matT, NSB * NBUCK, hdr + 11, desc2);   // chunk offsets; total->Etot
  coarse_scatter_k<<<NSB, 256, 0, stream>>>(ei, cluster, matT, keys);
  subgrp_k<<<NBUCK, 256, 0, stream>>>(keys, keys2, matT, hdr, cs_off, grp_cnt,
                                      headmask, nb_small, nb_big);
  sort_big_k<<<256, 256, 0, stream>>>(keys2, cs_off, nb_big, hdr, grp_cnt);
  scan1(grp_cnt, grp_base, NCS + 1, nullptr, desc3);
  emit_small_k<<<4096, 256, 0, stream>>>(keys2, cs_off, nb_small, hdr, grp_base,
                                         headmask, ea,
                                         out + OE, out + OE + EE, out + OA);
  emit_big_k<<<256, 256, 0, stream>>>(keys2, cs_off, nb_big, hdr, grp_base, ea,
                                      out + OE, out + OE + EE, out + OA);
  tail_fill_k<<<512, 256, 0, stream>>>(grp_base, out + OE, out + OE + EE, out + OA);
}

// Round 13
// 451.761 us; speedup vs baseline: 1.5096x; 1.1241x over previous
//
#include <hip/hip_runtime.h>

#define NN 300000
#define FF 64
#define EE 2400000
#define FEA 8
#define RAWCAP 131072   // >= 8*129*97 = 100104 (so cluster ids < 2^17)
#define NCS 131072      // cs id space (== RAWCAP)
#define NBUCK 2048      // coarse buckets: cb = cs>>6
#define NSB 512         // scatter blocks
#define TILE ((EE + NSB - 1) / NSB)
#define CAP 4096        // LDS capacity per coarse bucket (mean ~1172, +85 sigma)

typedef unsigned long long ull;

__device__ __forceinline__ unsigned fenc(float f) {
  unsigned b = __float_as_uint(f);
  return (b & 0x80000000u) ? ~b : (b | 0x80000000u);
}
__device__ __forceinline__ float fdec(unsigned e) {
  unsigned b = (e & 0x80000000u) ? (e ^ 0x80000000u) : ~e;
  return __uint_as_float(b);
}

__global__ void init_hdr_k(unsigned* hdr) {
  if (threadIdx.x == 0) {
    hdr[0] = 0xFFFFFFFFu; hdr[1] = 0xFFFFFFFFu;  // min enc
    hdr[2] = 0u;          hdr[3] = 0u;           // max enc
  }
}

__global__ void minmax_k(const float* __restrict__ pos, unsigned* hdr) {
  __shared__ unsigned red[4][4];
  int t = blockIdx.x * blockDim.x + threadIdx.x;
  float mnx = 1e30f, mny = 1e30f, mxx = -1e30f, mxy = -1e30f;
  for (int i = t; i < NN; i += gridDim.x * blockDim.x) {
    float px = pos[i * 3 + 1], py = pos[i * 3 + 2];
    mnx = fminf(mnx, px); mny = fminf(mny, py);
    mxx = fmaxf(mxx, px); mxy = fmaxf(mxy, py);
  }
  for (int o = 1; o < 64; o <<= 1) {
    mnx = fminf(mnx, __shfl_xor(mnx, o));
    mny = fminf(mny, __shfl_xor(mny, o));
    mxx = fmaxf(mxx, __shfl_xor(mxx, o));
    mxy = fmaxf(mxy, __shfl_xor(mxy, o));
  }
  int wid = threadIdx.x >> 6;
  if ((threadIdx.x & 63) == 0) {
    red[wid][0] = fenc(mnx); red[wid][1] = fenc(mny);
    red[wid][2] = fenc(mxx); red[wid][3] = fenc(mxy);
  }
  __syncthreads();
  if (threadIdx.x == 0) {
    unsigned a0 = red[0][0], a1 = red[0][1], a2 = red[0][2], a3 = red[0][3];
    for (int k = 1; k < 4; k++) {
      a0 = min(a0, red[k][0]); a1 = min(a1, red[k][1]);
      a2 = max(a2, red[k][2]); a3 = max(a3, red[k][3]);
    }
    atomicMin(&hdr[0], a0); atomicMin(&hdr[1], a1);
    atomicMax(&hdr[2], a2); atomicMax(&hdr[3], a3);
  }
}

__global__ void dims_k(unsigned* hdr) {
  if (threadIdx.x == 0 && blockIdx.x == 0) {
    float mnx = fdec(hdr[0]), mny = fdec(hdr[1]);
    float mxx = fdec(hdr[2]), mxy = fdec(hdr[3]);
    int d0 = (int)(floorf((mxx - mnx) / 5.0f) + 1.0f);
    int d1 = (int)(floorf((mxy - mny) / 5.0f) + 1.0f);
    hdr[4] = (unsigned)d0;
    hdr[5] = (unsigned)d1;
    ((float*)hdr)[6] = mnx;
    ((float*)hdr)[7] = mny;
  }
}

__global__ void raw_k(const float* __restrict__ pos, const int* __restrict__ batch,
                      const unsigned* __restrict__ hdr, int* __restrict__ cluster,
                      unsigned* __restrict__ flags) {
  int i = blockIdx.x * blockDim.x + threadIdx.x;
  if (i >= NN) return;
  float mnx = ((const float*)hdr)[6], mny = ((const float*)hdr)[7];
  int d0 = (int)hdr[4], d1 = (int)hdr[5];
  int c0 = (int)floorf((pos[i * 3 + 1] - mnx) / 5.0f);
  int c1 = (int)floorf((pos[i * 3 + 2] - mny) / 5.0f);
  int raw = batch[i] * (d0 * d1) + c0 * d1 + c1;
  cluster[i] = raw;
  flags[raw] = 1u;
}

// single-kernel exclusive scan: decoupled lookback (validated r8-r12)
__global__ void __launch_bounds__(256)
scan_lb_k(const unsigned* __restrict__ in, unsigned* __restrict__ out, int ntot,
          unsigned* __restrict__ total_out, ull* __restrict__ desc, int nb) {
  __shared__ unsigned sc[256];
  __shared__ unsigned s_pref;
  int bid = blockIdx.x;
  int base = bid * 1024 + threadIdx.x * 4;
  unsigned v[4]; unsigned s = 0;
#pragma unroll
  for (int k = 0; k < 4; k++) {
    int i = base + k;
    v[k] = (i < ntot) ? in[i] : 0u;
    s += v[k];
  }
  sc[threadIdx.x] = s;
  __syncthreads();
  unsigned xv = s;
  for (int o = 1; o < 256; o <<= 1) {
    unsigned y = (threadIdx.x >= o) ? sc[threadIdx.x - o] : 0u;
    __syncthreads();
    xv += y;
    sc[threadIdx.x] = xv;
    __syncthreads();
  }
  unsigned btot = sc[255];
  if (threadIdx.x == 0) {
    unsigned ex = 0;
    if (bid == 0) {
      atomicExch(&desc[0], (2ULL << 32) | (ull)btot);
    } else {
      atomicExch(&desc[bid], (1ULL << 32) | (ull)btot);
      int p = bid - 1;
      while (true) {
        ull d = atomicAdd(&desc[p], 0ULL);
        unsigned fl = (unsigned)(d >> 32);
        if (fl == 2u) { ex += (unsigned)d; break; }
        if (fl == 1u) { ex += (unsigned)d; --p; }
      }
      atomicExch(&desc[bid], (2ULL << 32) | (ull)(ex + btot));
    }
    s_pref = ex;
    if (total_out && bid == nb - 1) *total_out = ex + btot;
  }
  __syncthreads();
  unsigned run = s_pref + xv - s;
#pragma unroll
  for (int k = 0; k < 4; k++) {
    int i = base + k;
    if (i < ntot) out[i] = run;
    run += v[k];
  }
}

// map raw->cluster id, count members, pack slot r into cluster: (r<<17)|cl
__global__ void node_cnt_k(const unsigned* __restrict__ rank, int* __restrict__ cluster,
                           unsigned* __restrict__ cnt) {
  int i = blockIdx.x * blockDim.x + threadIdx.x;
  if (i >= NN) return;
  unsigned cl = rank[cluster[i]];
  unsigned r = atomicAdd(&cnt[cl], 1u);
  cluster[i] = (int)((r << 17) | cl);
}

// atomic-free: position = node_off[cl] + packed slot
__global__ void node_scatter_k(const int* __restrict__ cluster,
                               const unsigned* __restrict__ node_off,
                               int* __restrict__ nlist) {
  int i = blockIdx.x * blockDim.x + threadIdx.x;
  if (i >= NN) return;
  unsigned c = (unsigned)cluster[i];
  nlist[node_off[c & 0x1FFFFu] + (c >> 17)] = i;
}

// one wave per cluster: gather member rows, fmax in registers, write once.
__global__ void __launch_bounds__(256)
cluster_reduce_k(const float* __restrict__ x, const float* __restrict__ pos,
                 const int* __restrict__ batch, const int* __restrict__ nlist,
                 const unsigned* __restrict__ node_off, const unsigned* __restrict__ hdr,
                 float* __restrict__ out_x, float* __restrict__ out_pos,
                 float* __restrict__ out_batch) {
  int w = (blockIdx.x * blockDim.x + threadIdx.x) >> 6;
  int nw = (gridDim.x * blockDim.x) >> 6;
  int f = threadIdx.x & 63;
  int ncl = (int)hdr[8];
  for (int c = w; c < ncl; c += nw) {
    unsigned o0 = node_off[c];
    int len = (int)(node_off[c + 1] - o0);
    float mx = -1e38f;
    long long ps = 0;
    for (int m = 0; m < len; m++) {
      int nd = nlist[o0 + m];
      mx = fmaxf(mx, x[(size_t)nd * FF + f]);
      if (f < 3) ps += (long long)llrintf(pos[nd * 3 + f] * 65536.0f);
    }
    out_x[(size_t)c * FF + f] = mx;
    if (f < 3) {
      float v = (float)((double)ps / 65536.0 / (double)len);
      if (f > 0) v = floorf(v / 4.0f);
      out_pos[c * 3 + f] = v;
    }
    if (f == 63) out_batch[c] = (float)batch[nlist[o0]];
  }
}

__global__ void node_tail_k(const unsigned* __restrict__ hdr,
                            float* __restrict__ out_x, float* __restrict__ out_pos,
                            float* __restrict__ out_batch) {
  int ncl = (int)hdr[8];
  int total = (NN - ncl) * FF;
  for (int i = blockIdx.x * blockDim.x + threadIdx.x; i < total;
       i += gridDim.x * blockDim.x) {
    int r = ncl + (i >> 6), f = i & 63;
    out_x[(size_t)r * FF + f] = 0.0f;
    if (f < 3) out_pos[r * 3 + f] = 0.0f;
    if (f == 0) out_batch[r] = -1.0f;
  }
}

// ---- edge pipeline ----

__global__ void __launch_bounds__(256)
coarse_cnt_k(const int* __restrict__ ei, const int* __restrict__ cluster,
             unsigned* __restrict__ mat) {
  __shared__ unsigned h[NBUCK];
  for (int i = threadIdx.x; i < NBUCK; i += 256) h[i] = 0u;
  __syncthreads();
  int t0 = blockIdx.x * TILE;
  for (int k = threadIdx.x; k < TILE; k += 256) {
    int t = t0 + k;
    if (t >= EE) break;
    unsigned s = (unsigned)cluster[ei[t]] & 0x1FFFFu;
    unsigned d = (unsigned)cluster[ei[EE + t]] & 0x1FFFFu;
    if (s != d) atomicAdd(&h[s >> 6], 1u);
  }
  __syncthreads();
  for (int i = threadIdx.x; i < NBUCK; i += 256)
    mat[(size_t)blockIdx.x * NBUCK + i] = h[i];
}

__global__ void transpose_k(const unsigned* __restrict__ mat, unsigned* __restrict__ matT) {
  int f = blockIdx.x * blockDim.x + threadIdx.x;
  if (f >= NSB * NBUCK) return;
  int cb = f / NSB, blk = f - cb * NSB;
  matT[f] = mat[(size_t)blk * NBUCK + cb];
}

// keys[p] = (s_low6 << 39) | (d << 22) | eid ; single-writer contiguous chunks
__global__ void __launch_bounds__(256)
coarse_scatter_k(const int* __restrict__ ei, const int* __restrict__ cluster,
                 const unsigned* __restrict__ matT, ull* __restrict__ keys) {
  __shared__ unsigned cur[NBUCK];
  for (int i = threadIdx.x; i < NBUCK; i += 256)
    cur[i] = matT[(size_t)i * NSB + blockIdx.x];
  __syncthreads();
  int t0 = blockIdx.x * TILE;
  for (int k = threadIdx.x; k < TILE; k += 256) {
    int t = t0 + k;
    if (t >= EE) break;
    unsigned s = (unsigned)cluster[ei[t]] & 0x1FFFFu;
    unsigned d = (unsigned)cluster[ei[EE + t]] & 0x1FFFFu;
    if (s == d) continue;
    unsigned p = atomicAdd(&cur[s >> 6], 1u);
    keys[p] = ((ull)(s & 63u) << 39) | ((ull)d << 22) | (unsigned)t;
  }
}

// FULLY FUSED grouping+emit: per coarse bucket -- 64-bin partition in LDS,
// per-element head detect, inline decoupled lookback for the global row base,
// then direct emit (ea gather + row write). No keys2 / headmask / grp scan.
__global__ void __launch_bounds__(256)
grp_emit_k(const ull* __restrict__ keys, const unsigned* __restrict__ matT,
           unsigned* __restrict__ hdr, ull* __restrict__ desc,
           const float* __restrict__ ea,
           float* __restrict__ out_src, float* __restrict__ out_dst,
           float* __restrict__ out_ea) {
  __shared__ ull sk2[CAP];
  __shared__ unsigned char hflag[CAP];
  __shared__ unsigned h[64], pre[65], cur[64], hc[64], hpre[64];
  __shared__ unsigned sG, sBase, sCnt;
  int cb = blockIdx.x;
  int tid = threadIdx.x;
  unsigned start = matT[(size_t)cb * NSB];
  unsigned end = (cb == NBUCK - 1) ? hdr[11] : matT[(size_t)(cb + 1) * NSB];
  int len = (int)(end - start);
  bool lds = (len <= CAP);
  unsigned G = 0;

  if (len > 0 && lds) {
    if (tid < 64) h[tid] = 0u;
    __syncthreads();
    for (int i = tid; i < len; i += 256)
      atomicAdd(&h[(unsigned)(keys[start + i] >> 39) & 63u], 1u);
    __syncthreads();
    if (tid == 0) {
      unsigned run = 0;
      for (int j = 0; j < 64; j++) { pre[j] = run; run += h[j]; }
      pre[64] = run;
    }
    __syncthreads();
    if (tid < 64) cur[tid] = pre[tid];
    __syncthreads();
    for (int i = tid; i < len; i += 256) {
      ull v = keys[start + i];                 // L2-hot second read
      unsigned j = (unsigned)(v >> 39) & 63u;
      sk2[atomicAdd(&cur[j], 1u)] = v;
    }
    __syncthreads();
    for (int i = tid; i < len; i += 256) {
      ull v = sk2[i];
      unsigned j = (unsigned)(v >> 39) & 63u;
      unsigned key23 = (unsigned)(v >> 22);
      bool head = true;
      for (int q = (int)pre[j]; q < i; ++q)
        if ((unsigned)(sk2[q] >> 22) == key23) { head = false; break; }
      hflag[i] = head ? 1 : 0;
    }
    __syncthreads();
    if (tid < 64) {
      unsigned c = 0;
      for (unsigned q = pre[tid]; q < pre[tid + 1]; ++q) c += hflag[q];
      hc[tid] = c;
    }
    __syncthreads();
    if (tid == 0) {
      unsigned run = 0;
      for (int j = 0; j < 64; j++) { hpre[j] = run; run += hc[j]; }
      sG = run;
    }
    __syncthreads();
    G = sG;
  } else if (len > 0) {
    // insurance (len > CAP, unreachable for this data): per-sub-bucket staging
    if (tid == 0) sG = 0;
    __syncthreads();
    for (int j = 0; j < 64; j++) {
      if (tid == 0) sCnt = 0;
      __syncthreads();
      for (int i = tid; i < len; i += 256) {
        ull v = keys[start + i];
        if (((unsigned)(v >> 39) & 63u) == (unsigned)j) {
          unsigned p = atomicAdd(&sCnt, 1u);
          if (p < CAP) sk2[p] = v;
        }
      }
      __syncthreads();
      int sl = min((int)sCnt, CAP);
      for (int i = tid; i < sl; i += 256) {
        unsigned key23 = (unsigned)(sk2[i] >> 22);
        bool head = true;
        for (int q = 0; q < i; ++q)
          if ((unsigned)(sk2[q] >> 22) == key23) { head = false; break; }
        hflag[i] = head ? 1 : 0;
      }
      __syncthreads();
      if (tid == 0) {
        unsigned c = 0;
        for (int q = 0; q < sl; ++q) c += hflag[q];
        hc[j] = c; hpre[j] = sG; sG += c;
      }
      __syncthreads();
    }
    G = sG;
  }

  // inline decoupled lookback over coarse buckets -> global row base
  if (tid == 0) {
    unsigned ex = 0;
    if (cb == 0) {
      atomicExch(&desc[0], (2ULL << 32) | (ull)G);
    } else {
      atomicExch(&desc[cb], (1ULL << 32) | (ull)G);
      int p = cb - 1;
      while (true) {
        ull d = atomicAdd(&desc[p], 0ULL);
        unsigned fl = (unsigned)(d >> 32);
        if (fl == 2u) { ex += (unsigned)d; break; }
        if (fl == 1u) { ex += (unsigned)d; --p; }
      }
      atomicExch(&desc[cb], (2ULL << 32) | (ull)(ex + G));
    }
    sBase = ex;
    if (cb == NBUCK - 1) hdr[12] = ex + G;   // total groups for tail_fill
  }
  __syncthreads();
  unsigned base = sBase;
  if (len <= 0) return;

  if (lds) {
    for (int i = tid; i < len; i += 256) {
      if (!hflag[i]) continue;
      ull v = sk2[i];
      unsigned j = (unsigned)(v >> 39) & 63u;
      unsigned key23 = (unsigned)(v >> 22);
      unsigned r = 0;
      for (unsigned q = pre[j]; q < pre[j + 1]; ++q)
        if (hflag[q] && (unsigned)(sk2[q] >> 22) < key23) r++;
      unsigned eid = (unsigned)(v & 0x3FFFFFULL);
      const float4* p4 = (const float4*)&ea[(size_t)eid * FEA];
      float4 a0 = p4[0], a1 = p4[1];
      bool single = (hc[j] == pre[j + 1] - pre[j]);
      if (!single) {
        for (unsigned q = pre[j]; q < pre[j + 1]; ++q) {
          if (q == (unsigned)i) continue;
          ull v2 = sk2[q];
          if ((unsigned)(v2 >> 22) == key23) {
            const float4* q4 = (const float4*)&ea[(size_t)(v2 & 0x3FFFFFULL) * FEA];
            float4 b0 = q4[0], b1 = q4[1];
            a0.x += b0.x; a0.y += b0.y; a0.z += b0.z; a0.w += b0.w;
            a1.x += b1.x; a1.y += b1.y; a1.z += b1.z; a1.w += b1.w;
          }
        }
      }
      unsigned row = base + hpre[j] + r;
      out_src[row] = (float)(cb * 64 + (int)j);
      out_dst[row] = (float)(key23 & 0x1FFFFu);
      float4* o = (float4*)&out_ea[(size_t)row * FEA];
      o[0] = a0; o[1] = a1;
    }
  } else {
    // insurance emit: redo per-sub-bucket staging and emit
    for (int j = 0; j < 64; j++) {
      if (tid == 0) sCnt = 0;
      __syncthreads();
      for (int i = tid; i < len; i += 256) {
        ull v = keys[start + i];
        if (((unsigned)(v >> 39) & 63u) == (unsigned)j) {
          unsigned p = atomicAdd(&sCnt, 1u);
          if (p < CAP) sk2[p] = v;
        }
      }
      __syncthreads();
      int sl = min((int)sCnt, CAP);
      for (int i = tid; i < sl; i += 256) {
        unsigned key23 = (unsigned)(sk2[i] >> 22);
        bool head = true;
        for (int q = 0; q < i; ++q)
          if ((unsigned)(sk2[q] >> 22) == key23) { head = false; break; }
        hflag[i] = head ? 1 : 0;
      }
      __syncthreads();
      for (int i = tid; i < sl; i += 256) {
        if (!hflag[i]) continue;
        ull v = sk2[i];
        unsigned key23 = (unsigned)(v >> 22);
        unsigned r = 0;
        for (int q = 0; q < sl; ++q)
          if (hflag[q] && (unsigned)(sk2[q] >> 22) < key23) r++;
        const float4* p4 = (const float4*)&ea[(size_t)(v & 0x3FFFFFULL) * FEA];
        float4 a0 = p4[0], a1 = p4[1];
        bool single = (hc[j] == (unsigned)sl);
        if (!single) {
          for (int q = 0; q < sl; ++q) {
            if (q == i) continue;
            ull v2 = sk2[q];
            if ((unsigned)(v2 >> 22) == key23) {
              const float4* q4 = (const float4*)&ea[(size_t)(v2 & 0x3FFFFFULL) * FEA];
              float4 b0 = q4[0], b1 = q4[1];
              a0.x += b0.x; a0.y += b0.y; a0.z += b0.z; a0.w += b0.w;
              a1.x += b1.x; a1.y += b1.y; a1.z += b1.z; a1.w += b1.w;
            }
          }
        }
        unsigned row = base + hpre[j] + r;
        out_src[row] = (float)(cb * 64 + j);
        out_dst[row] = (float)(key23 & 0x1FFFFu);
        float4* o = (float4*)&out_ea[(size_t)row * FEA];
        o[0] = a0; o[1] = a1;
      }
      __syncthreads();
    }
  }
}

// rows >= T get -1/-1 and zero ea (T = hdr[12] from grp_emit)
__global__ void tail_fill_k(const unsigned* __restrict__ hdr,
                            float* __restrict__ out_src, float* __restrict__ out_dst,
                            float* __restrict__ out_ea) {
  int T = (int)hdr[12];
  for (int t = T + blockIdx.x * blockDim.x + threadIdx.x; t < EE;
       t += gridDim.x * blockDim.x) {
    out_src[t] = -1.0f;
    out_dst[t] = -1.0f;
    float4 z = make_float4(0.f, 0.f, 0.f, 0.f);
    float4* o = (float4*)&out_ea[(size_t)t * FEA];
    o[0] = z; o[1] = z;
  }
}

extern "C" void kernel_launch(void* const* d_in, const int* in_sizes, int n_in,
                              void* d_out, int out_size, void* d_ws, size_t ws_size,
                              hipStream_t stream) {
  const float* x   = (const float*)d_in[0];
  const float* pos = (const float*)d_in[1];
  const int* batch = (const int*)d_in[2];
  const int* ei    = (const int*)d_in[3];
  const float* ea  = (const float*)d_in[4];
  float* out = (float*)d_out;

  const size_t OX = 0;
  const size_t OP = (size_t)NN * FF;
  const size_t OB = OP + (size_t)NN * 3;
  const size_t OE = OB + (size_t)NN;
  const size_t OA = OE + (size_t)2 * EE;

  char* w = (char*)d_ws;
  size_t woff = 0;
  auto alloc = [&](size_t bytes) -> void* {
    void* p = w + woff;
    woff += (bytes + 255) & ~(size_t)255;
    return p;
  };
  // zeroed region (one memset)
  unsigned* rank    = (unsigned*)alloc((size_t)RAWCAP * 4);
  unsigned* cnt     = (unsigned*)alloc((size_t)(NN + 1) * 4);
  ull* desc0        = (ull*)alloc(2048 * 8);
  ull* desc1        = (ull*)alloc(2048 * 8);
  ull* desc2        = (ull*)alloc(2048 * 8);
  ull* desc3        = (ull*)alloc(2048 * 8);
  size_t zero_bytes = woff;
  // written-before-read region
  int* cluster      = (int*)alloc((size_t)NN * 4);
  int* nlist        = (int*)alloc((size_t)NN * 4);
  unsigned* node_off= (unsigned*)alloc((size_t)(NN + 2) * 4);
  unsigned* mat     = (unsigned*)alloc((size_t)NSB * NBUCK * 4);
  unsigned* matT    = (unsigned*)alloc((size_t)NSB * NBUCK * 4);
  unsigned* hdr     = (unsigned*)alloc(256);
  ull* keys         = (ull*)alloc((size_t)EE * 8);

  hipMemsetAsync(d_ws, 0, zero_bytes, stream);

  init_hdr_k<<<1, 64, 0, stream>>>(hdr);
  minmax_k<<<128, 256, 0, stream>>>(pos, hdr);
  dims_k<<<1, 64, 0, stream>>>(hdr);
  raw_k<<<(NN + 255) / 256, 256, 0, stream>>>(pos, batch, hdr, cluster, rank);

  auto scan1 = [&](const unsigned* in_, unsigned* out_, int ntot,
                   unsigned* total_out, ull* d_) {
    int nb = (ntot + 1023) / 1024;
    scan_lb_k<<<nb, 256, 0, stream>>>(in_, out_, ntot, total_out, d_, nb);
  };
  scan1(rank, rank, RAWCAP, hdr + 8, desc0);   // rank[raw]=cluster id; total->ncl

  node_cnt_k<<<(NN + 255) / 256, 256, 0, stream>>>(rank, cluster, cnt);
  scan1(cnt, node_off, NN + 1, nullptr, desc1);
  node_scatter_k<<<(NN + 255) / 256, 256, 0, stream>>>(cluster, node_off, nlist);
  cluster_reduce_k<<<2048, 256, 0, stream>>>(x, pos, batch, nlist, node_off, hdr,
                                             out + OX, out + OP, out + OB);
  node_tail_k<<<2048, 256, 0, stream>>>(hdr, out + OX, out + OP, out + OB);

  coarse_cnt_k<<<NSB, 256, 0, stream>>>(ei, cluster, mat);
  transpose_k<<<(NSB * NBUCK + 255) / 256, 256, 0, stream>>>(mat, matT);
  scan1(matT, matT, NSB * NBUCK, hdr + 11, desc2);   // chunk offsets; total->Etot
  coarse_scatter_k<<<NSB, 256, 0, stream>>>(ei, cluster, matT, keys);
  grp_emit_k<<<NBUCK, 256, 0, stream>>>(keys, matT, hdr, desc3, ea,
                                        out + OE, out + OE + EE, out + OA);
  tail_fill_k<<<512, 256, 0, stream>>>(hdr, out + OE, out + OE + EE, out + OA);
}